// Round 8
// baseline (710.010 us; speedup 1.0000x reference)
//
#include <hip/hip_runtime.h>
#include <hip/hip_bf16.h>
#include <math.h>

#define NNODES 100000
#define NEDGES 1600000
#define FIN 256
#define HDIM 128
#define NGRAPH 128
#define NCLS 10
#define NEG 0.2f

#define NBUCK 98            // buckets of 1024 dst nodes (100000 >> 10 -> 0..97)
#define EPB 4096            // edges per bin_place block
#define EBLK ((NEDGES + EPB - 1) / EPB)   // 391

typedef short bf8 __attribute__((ext_vector_type(8)));
typedef float f4 __attribute__((ext_vector_type(4)));

__device__ __forceinline__ float lrelu(float x) { return x > 0.f ? x : NEG * x; }

__device__ __forceinline__ unsigned short f2bf(float f) {
  union { float f; unsigned int u; } v; v.f = f;
  unsigned int r = v.u + 0x7fffu + ((v.u >> 16) & 1u);   // round-nearest-even
  return (unsigned short)(r >> 16);
}
__device__ __forceinline__ float bf_lo(unsigned int p) {
  union { unsigned int u; float f; } v; v.u = p << 16; return v.f;
}
__device__ __forceinline__ float bf_hi(unsigned int p) {
  union { unsigned int u; float f; } v; v.u = p & 0xffff0000u; return v.f;
}

// ---------------- one-shot weight convert+transpose: w[K][128] -> wt[128][K] -
__global__ __launch_bounds__(256) void convert_transpose(const float* __restrict__ w,
                                                         unsigned short* __restrict__ wt,
                                                         int K) {
  int i = blockIdx.x * 256 + threadIdx.x;
  if (i >= K * 128) return;
  int k = i >> 7, n = i & 127;
  wt[n * K + k] = f2bf(w[(size_t)k * 128 + n]);
}

// ---------------- MFMA GEMM (+ optional fused attention-logit epilogue) ------
__global__ __launch_bounds__(256) void gemm_mfma(const float* __restrict__ A,
                                                 const unsigned short* __restrict__ Bt,
                                                 const float* __restrict__ bias,
                                                 float* __restrict__ C,
                                                 unsigned int* __restrict__ Cp,
                                                 const float* __restrict__ a_src,
                                                 const float* __restrict__ a_dst,
                                                 float* __restrict__ o_as,
                                                 float* __restrict__ o_ad,
                                                 int M, int K, int dorelu) {
  __shared__ bf8 As[512];
  __shared__ bf8 Bs[512];
  int tid = threadIdx.x;
  int wv = tid >> 6, lane = tid & 63;
  int quad = lane >> 4, m16 = lane & 15;
  int row0 = blockIdx.x * 128;

  f4 acc[2][8];
#pragma unroll
  for (int a = 0; a < 2; ++a)
#pragma unroll
    for (int b = 0; b < 8; ++b) acc[a][b] = (f4){0.f, 0.f, 0.f, 0.f};

  for (int kb = 0; kb < K; kb += 32) {
    __syncthreads();
#pragma unroll
    for (int bb = 0; bb < 2; ++bb) {
      int b = tid + bb * 256;
      int l = b & 63, mt = b >> 6;
      int row = row0 + mt * 16 + (l & 15);
      if (row > M - 1) row = M - 1;
      const float* src = &A[(size_t)row * K + kb + (l >> 4) * 8];
      float4 x0 = *reinterpret_cast<const float4*>(src);
      float4 x1 = *reinterpret_cast<const float4*>(src + 4);
      bf8 v;
      v[0] = (short)f2bf(x0.x); v[1] = (short)f2bf(x0.y);
      v[2] = (short)f2bf(x0.z); v[3] = (short)f2bf(x0.w);
      v[4] = (short)f2bf(x1.x); v[5] = (short)f2bf(x1.y);
      v[6] = (short)f2bf(x1.z); v[7] = (short)f2bf(x1.w);
      As[b] = v;
    }
#pragma unroll
    for (int bb = 0; bb < 2; ++bb) {
      int b = tid + bb * 256;
      int l = b & 63, tn = b >> 6;
      int n = tn * 16 + (l & 15);
      Bs[b] = *reinterpret_cast<const bf8*>(&Bt[(size_t)n * K + kb + (l >> 4) * 8]);
    }
    __syncthreads();
    bf8 af0 = As[(wv * 2 + 0) * 64 + lane];
    bf8 af1 = As[(wv * 2 + 1) * 64 + lane];
#pragma unroll
    for (int tn = 0; tn < 8; ++tn) {
      bf8 bfm = Bs[tn * 64 + lane];
      acc[0][tn] = __builtin_amdgcn_mfma_f32_16x16x32_bf16(af0, bfm, acc[0][tn], 0, 0, 0);
      acc[1][tn] = __builtin_amdgcn_mfma_f32_16x16x32_bf16(af1, bfm, acc[1][tn], 0, 0, 0);
    }
  }

  if (Cp) {
    if (a_src) {
      float aS[8], aD[8];
#pragma unroll
      for (int tn = 0; tn < 4; ++tn) {
        aS[tn]     = a_src[tn * 16 + m16];
        aS[tn + 4] = a_src[64 + tn * 16 + m16];
        aD[tn]     = a_dst[tn * 16 + m16];
        aD[tn + 4] = a_dst[64 + tn * 16 + m16];
      }
#pragma unroll
      for (int mt = 0; mt < 2; ++mt)
#pragma unroll
        for (int r = 0; r < 4; ++r) {
          int row = row0 + wv * 32 + mt * 16 + quad * 4 + r;
          float ps0 = 0.f, ps1 = 0.f, pd0 = 0.f, pd1 = 0.f;
#pragma unroll
          for (int tn = 0; tn < 4; ++tn) {
            float v0 = acc[mt][tn][r], v1 = acc[mt][tn + 4][r];
            ps0 = fmaf(v0, aS[tn], ps0);
            ps1 = fmaf(v1, aS[tn + 4], ps1);
            pd0 = fmaf(v0, aD[tn], pd0);
            pd1 = fmaf(v1, aD[tn + 4], pd1);
          }
#pragma unroll
          for (int o = 8; o; o >>= 1) {
            ps0 += __shfl_xor(ps0, o); ps1 += __shfl_xor(ps1, o);
            pd0 += __shfl_xor(pd0, o); pd1 += __shfl_xor(pd1, o);
          }
          if (m16 == 0 && row < M) {
            o_as[2 * row] = ps0; o_as[2 * row + 1] = ps1;
            o_ad[2 * row] = pd0; o_ad[2 * row + 1] = pd1;
          }
        }
    }
#pragma unroll
    for (int mt = 0; mt < 2; ++mt)
#pragma unroll
      for (int tn = 0; tn < 4; ++tn)
#pragma unroll
        for (int r = 0; r < 4; ++r) {
          int row = row0 + wv * 32 + mt * 16 + quad * 4 + r;
          if (row < M) {
            unsigned int p = (unsigned int)f2bf(acc[mt][tn][r]) |
                             ((unsigned int)f2bf(acc[mt][tn + 4][r]) << 16);
            Cp[(size_t)row * 64 + tn * 16 + m16] = p;
          }
        }
  } else {
#pragma unroll
    for (int mt = 0; mt < 2; ++mt)
#pragma unroll
      for (int tn = 0; tn < 8; ++tn) {
        float bv = bias ? bias[tn * 16 + m16] : 0.f;
#pragma unroll
        for (int r = 0; r < 4; ++r) {
          int row = row0 + wv * 32 + mt * 16 + quad * 4 + r;
          if (row < M) {
            float v = acc[mt][tn][r] + bv;
            if (dorelu) v = fmaxf(v, 0.f);
            C[(size_t)row * 128 + tn * 16 + m16] = v;
          }
        }
      }
  }
}

// ---------------- graph boundaries (batch is sorted) -------------------------
__global__ void find_starts(const int* __restrict__ batch, int* __restrict__ gstart) {
  int g = threadIdx.x;
  if (g > NGRAPH) return;
  if (g == NGRAPH) { gstart[g] = NNODES; return; }
  int lo = 0, hi = NNODES;
  while (lo < hi) { int mid = (lo + hi) >> 1; if (batch[mid] < g) lo = mid + 1; else hi = mid; }
  gstart[g] = lo;
}

// ======== CSR build, bucketed two-phase (no random global atomics) ==========
__global__ __launch_bounds__(256) void bin_count(const int* __restrict__ edst,
                                                 int* __restrict__ blockHist) {
  __shared__ int hist[NBUCK];
  int t = threadIdx.x, blk = blockIdx.x;
  if (t < NBUCK) hist[t] = 0;
  __syncthreads();
  int e0 = blk * EPB;
#pragma unroll
  for (int it = 0; it < EPB / 256; ++it) {
    int e = e0 + it * 256 + t;
    if (e < NEDGES) atomicAdd(&hist[((unsigned)edst[e]) >> 10], 1);
  }
  __syncthreads();
  if (t < NBUCK) blockHist[blk * NBUCK + t] = hist[t];
}

__global__ __launch_bounds__(512) void colscan(const int* __restrict__ blockHist,
                                               int* __restrict__ blockBaseCol,
                                               int* __restrict__ bucket_total) {
  __shared__ int s[512];
  int b = blockIdx.x, t = threadIdx.x;
  int v = (t < EBLK) ? blockHist[t * NBUCK + b] : 0;
  s[t] = v;
  __syncthreads();
  for (int off = 1; off < 512; off <<= 1) {
    int u = (t >= off) ? s[t - off] : 0;
    __syncthreads();
    s[t] += u;
    __syncthreads();
  }
  if (t < EBLK) blockBaseCol[b * EBLK + t] = s[t] - v;
  if (t == 511) bucket_total[b] = s[511];
}

__global__ __launch_bounds__(128) void bscan(const int* __restrict__ bucket_total,
                                             int* __restrict__ bucket_ptr) {
  __shared__ int s[128];
  int t = threadIdx.x;
  int v = (t < NBUCK) ? bucket_total[t] : 0;
  s[t] = v;
  __syncthreads();
  for (int off = 1; off < 128; off <<= 1) {
    int u = (t >= off) ? s[t - off] : 0;
    __syncthreads();
    s[t] += u;
    __syncthreads();
  }
  if (t < NBUCK) bucket_ptr[t] = s[t] - v;
  if (t == 127) bucket_ptr[NBUCK] = s[127];
}

__global__ __launch_bounds__(512) void bin_place(const int* __restrict__ esrc,
                                                 const int* __restrict__ edst,
                                                 const int* __restrict__ blockBaseCol,
                                                 const int* __restrict__ bucket_ptr,
                                                 uint2* __restrict__ stagingG) {
  __shared__ int hist[NBUCK + 1], lbase[NBUCK + 1], lcur[NBUCK + 1], cbase[NBUCK];
  __shared__ int tmp[128];
  __shared__ uint2 st[EPB];
  int t = threadIdx.x, blk = blockIdx.x;
  if (t < NBUCK + 1) hist[t] = 0;
  __syncthreads();
  int e0 = blk * EPB;
#pragma unroll
  for (int it = 0; it < EPB / 512; ++it) {
    int e = e0 + it * 512 + t;
    int b = NBUCK;
    if (e < NEDGES) b = ((unsigned)edst[e]) >> 10;
    atomicAdd(&hist[b], 1);
  }
  __syncthreads();
  if (t < 128) tmp[t] = (t < NBUCK + 1) ? hist[t] : 0;
  __syncthreads();
  for (int off = 1; off < 128; off <<= 1) {
    int u = 0;
    if (t < 128 && t >= off) u = tmp[t - off];
    __syncthreads();
    if (t < 128) tmp[t] += u;
    __syncthreads();
  }
  if (t < NBUCK + 1) { int ex = tmp[t] - hist[t]; lbase[t] = ex; lcur[t] = ex; }
  if (t < NBUCK) cbase[t] = bucket_ptr[t] + blockBaseCol[t * EBLK + blk];
  __syncthreads();
#pragma unroll
  for (int it = 0; it < EPB / 512; ++it) {
    int e = e0 + it * 512 + t;
    unsigned s = 0, d = 0xFFFFFFFFu;
    if (e < NEDGES) { s = (unsigned)esrc[e]; d = (unsigned)edst[e]; }
    int b = (d == 0xFFFFFFFFu) ? NBUCK : (int)(d >> 10);
    int slot = atomicAdd(&lcur[b], 1);
    st[slot] = make_uint2(s, d);
  }
  __syncthreads();
  for (int i = t; i < EPB; i += 512) {
    uint2 ed = st[i];
    if (ed.y == 0xFFFFFFFFu) continue;
    int b = (int)(ed.y >> 10);
    stagingG[cbase[b] + (i - lbase[b])] = ed;
  }
}

__global__ __launch_bounds__(1024) void bucket_deg(const uint2* __restrict__ stagingG,
                                                   const int* __restrict__ bucket_ptr,
                                                   int* __restrict__ deg) {
  __shared__ int dl[1024];
  int b = blockIdx.x, t = threadIdx.x;
  dl[t] = 0;
  __syncthreads();
  int s0 = bucket_ptr[b], s1 = bucket_ptr[b + 1];
  for (int j = s0 + t; j < s1; j += 1024)
    atomicAdd(&dl[stagingG[j].y & 1023], 1);
  __syncthreads();
  int n = (b << 10) + t;
  if (n < NNODES) deg[n] = dl[t];
}

__global__ __launch_bounds__(256) void scan_block(const int* __restrict__ deg,
                                                  int* __restrict__ incl,
                                                  int* __restrict__ blocksum) {
  __shared__ int s[256];
  int tid = threadIdx.x;
  int i = blockIdx.x * 256 + tid;
  s[tid] = (i < NNODES) ? deg[i] : 0;
  __syncthreads();
  for (int off = 1; off < 256; off <<= 1) {
    int t = (tid >= off) ? s[tid - off] : 0;
    __syncthreads();
    s[tid] += t;
    __syncthreads();
  }
  if (i < NNODES) incl[i] = s[tid];
  if (tid == 255) blocksum[blockIdx.x] = s[255];
}

__global__ void scan_offsets(int* blocksum, int nb) {
  if (threadIdx.x == 0 && blockIdx.x == 0) {
    int run = 0;
    for (int b = 0; b < nb; ++b) { int t = blocksum[b]; blocksum[b] = run; run += t; }
  }
}

__global__ __launch_bounds__(256) void finalize_csr(const int* __restrict__ deg,
                                                    const int* __restrict__ incl,
                                                    const int* __restrict__ blocksum,
                                                    int* __restrict__ row_ptr) {
  int i = blockIdx.x * 256 + threadIdx.x;
  if (i >= NNODES) return;
  int tot = incl[i] + blocksum[i >> 8];
  row_ptr[i] = tot - deg[i];
  if (i == NNODES - 1) row_ptr[NNODES] = tot;
}

__global__ __launch_bounds__(1024) void bucket_csr(const uint2* __restrict__ stagingG,
                                                   const int* __restrict__ bucket_ptr,
                                                   const int* __restrict__ row_ptr,
                                                   int* __restrict__ colv) {
  __shared__ int cur[1024];
  int b = blockIdx.x, t = threadIdx.x;
  int n = (b << 10) + t;
  cur[t] = (n < NNODES) ? row_ptr[n] : 0;
  __syncthreads();
  int s0 = bucket_ptr[b], s1 = bucket_ptr[b + 1];
  for (int j = s0 + t; j < s1; j += 1024) {
    uint2 e = stagingG[j];
    int pos = atomicAdd(&cur[e.y & 1023], 1);
    colv[pos] = (int)e.x;
  }
}

// ---------------- quad-edge gather: one dwordx4 serves 4 edges ---------------
// lane L: edge t + (L>>4), channel-pairs (L&15)*4..+4 of the packed hwb row.
template<int T>
__device__ __forceinline__ void gather4(const unsigned int* __restrict__ hwb,
                                        const int* __restrict__ rowsW,
                                        const float2* __restrict__ wW,
                                        int grp, int cg4,
                                        float* A0, float* A1) {
#pragma unroll
  for (int t = 0; t < T; t += 4) {
    int e = t + grp;
    int row = rowsW[e];
    float2 w = wW[e];
    uint4 q = *reinterpret_cast<const uint4*>(&hwb[(size_t)row * 64 + cg4]);
    A0[0] = fmaf(w.x, bf_lo(q.x), A0[0]); A1[0] = fmaf(w.y, bf_hi(q.x), A1[0]);
    A0[1] = fmaf(w.x, bf_lo(q.y), A0[1]); A1[1] = fmaf(w.y, bf_hi(q.y), A1[1]);
    A0[2] = fmaf(w.x, bf_lo(q.z), A0[2]); A1[2] = fmaf(w.y, bf_hi(q.z), A1[2]);
    A0[3] = fmaf(w.x, bf_lo(q.w), A0[3]); A1[3] = fmaf(w.y, bf_hi(q.w), A1[3]);
  }
}

// ---------------- softmax aggregation: one wave per dst node -----------------
__global__ __launch_bounds__(256) void aggregate(const unsigned int* __restrict__ hwb,
                                                 const float* __restrict__ a_s,
                                                 const float* __restrict__ a_d,
                                                 const int* __restrict__ row_ptr,
                                                 const int* __restrict__ colv,
                                                 const float* __restrict__ bias,
                                                 float* __restrict__ out) {
  __shared__ int   rowsS[4][64];
  __shared__ float2 wS[4][64];
  int tid = threadIdx.x;
  int wv = tid >> 6, lane = tid & 63;
  int i = (blockIdx.x * 256 + tid) >> 6;
  if (i >= NNODES) return;
  int grp = lane >> 4, cg4 = (lane & 15) * 4;

  float ad0 = a_d[2 * i], ad1 = a_d[2 * i + 1];
  float es0 = lrelu(a_s[2 * i] + ad0), es1 = lrelu(a_s[2 * i + 1] + ad1);  // self edge
  int start = row_ptr[i], end = row_ptr[i + 1];
  int deg = end - start;

  int sl = 0; float e0l = -1e30f, e1l = -1e30f;
  if (lane < deg) {
    sl = colv[start + lane];
    float2 av = *reinterpret_cast<const float2*>(&a_s[2 * sl]);
    e0l = lrelu(av.x + ad0); e1l = lrelu(av.y + ad1);
  }
  float m0 = fmaxf(es0, e0l), m1 = fmaxf(es1, e1l);
  for (int j = start + 64 + lane; j < end; j += 64) {
    int s = colv[j];
    float2 av = *reinterpret_cast<const float2*>(&a_s[2 * s]);
    m0 = fmaxf(m0, lrelu(av.x + ad0));
    m1 = fmaxf(m1, lrelu(av.y + ad1));
  }
  for (int o = 32; o; o >>= 1) {
    m0 = fmaxf(m0, __shfl_xor(m0, o));
    m1 = fmaxf(m1, __shfl_xor(m1, o));
  }
  float w0l = lane < deg ? __expf(e0l - m0) : 0.f;
  float w1l = lane < deg ? __expf(e1l - m1) : 0.f;
  float d0 = w0l, d1 = w1l;
  for (int o = 32; o; o >>= 1) { d0 += __shfl_xor(d0, o); d1 += __shfl_xor(d1, o); }
  float ws0 = __expf(es0 - m0), ws1 = __expf(es1 - m1);
  float den0 = d0 + ws0, den1 = d1 + ws1;

  // stage edge rows + weights for this wave (ghost lanes: sl=0, w=0)
  rowsS[wv][lane] = sl;
  wS[wv][lane] = make_float2(w0l, w1l);

  // accumulators: lane covers channel-pairs cg4..cg4+3; self only in grp 0
  float A0[4] = {0.f, 0.f, 0.f, 0.f}, A1[4] = {0.f, 0.f, 0.f, 0.f};
  {
    uint4 qs = *reinterpret_cast<const uint4*>(&hwb[(size_t)i * 64 + cg4]);
    if (grp == 0) {
      A0[0] = ws0 * bf_lo(qs.x); A1[0] = ws1 * bf_hi(qs.x);
      A0[1] = ws0 * bf_lo(qs.y); A1[1] = ws1 * bf_hi(qs.y);
      A0[2] = ws0 * bf_lo(qs.z); A1[2] = ws1 * bf_hi(qs.z);
      A0[3] = ws0 * bf_lo(qs.w); A1[3] = ws1 * bf_hi(qs.w);
    }
  }
  int dmin = deg < 64 ? deg : 64;
  const int* rowsW = rowsS[wv];
  const float2* wW = wS[wv];
  switch ((dmin + 15) >> 4) {
    case 1: gather4<16>(hwb, rowsW, wW, grp, cg4, A0, A1); break;
    case 2: gather4<32>(hwb, rowsW, wW, grp, cg4, A0, A1); break;
    case 3: gather4<48>(hwb, rowsW, wW, grp, cg4, A0, A1); break;
    case 4: gather4<64>(hwb, rowsW, wW, grp, cg4, A0, A1); break;
    default: break;
  }
  // rare overflow (deg > 64): group-strided edges, den delta reduced separately
  float dd0 = 0.f, dd1 = 0.f;
  for (int j = start + 64 + grp; j < end; j += 4) {
    int s = colv[j];
    float2 av = *reinterpret_cast<const float2*>(&a_s[2 * s]);
    float w0 = __expf(lrelu(av.x + ad0) - m0);
    float w1 = __expf(lrelu(av.y + ad1) - m1);
    dd0 += w0; dd1 += w1;
    uint4 q = *reinterpret_cast<const uint4*>(&hwb[(size_t)s * 64 + cg4]);
    A0[0] = fmaf(w0, bf_lo(q.x), A0[0]); A1[0] = fmaf(w1, bf_hi(q.x), A1[0]);
    A0[1] = fmaf(w0, bf_lo(q.y), A0[1]); A1[1] = fmaf(w1, bf_hi(q.y), A1[1]);
    A0[2] = fmaf(w0, bf_lo(q.z), A0[2]); A1[2] = fmaf(w1, bf_hi(q.z), A1[2]);
    A0[3] = fmaf(w0, bf_lo(q.w), A0[3]); A1[3] = fmaf(w1, bf_hi(q.w), A1[3]);
  }
  if (deg > 64) {
    dd0 += __shfl_xor(dd0, 16); dd0 += __shfl_xor(dd0, 32);
    dd1 += __shfl_xor(dd1, 16); dd1 += __shfl_xor(dd1, 32);
    den0 += dd0; den1 += dd1;
  }
  // fold the 4 edge-subsets (groups)
#pragma unroll
  for (int j = 0; j < 4; ++j) {
    A0[j] += __shfl_xor(A0[j], 16); A0[j] += __shfl_xor(A0[j], 32);
    A1[j] += __shfl_xor(A1[j], 16); A1[j] += __shfl_xor(A1[j], 32);
  }
  // write: grp0 -> head0 float4, grp1 -> head1 float4
  if (grp == 0) {
    float4 o;
    o.x = fmaxf(A0[0] / den0 + bias[cg4 + 0], 0.f);
    o.y = fmaxf(A0[1] / den0 + bias[cg4 + 1], 0.f);
    o.z = fmaxf(A0[2] / den0 + bias[cg4 + 2], 0.f);
    o.w = fmaxf(A0[3] / den0 + bias[cg4 + 3], 0.f);
    *reinterpret_cast<float4*>(&out[(size_t)i * 128 + cg4]) = o;
  } else if (grp == 1) {
    float4 o;
    o.x = fmaxf(A1[0] / den1 + bias[64 + cg4 + 0], 0.f);
    o.y = fmaxf(A1[1] / den1 + bias[64 + cg4 + 1], 0.f);
    o.z = fmaxf(A1[2] / den1 + bias[64 + cg4 + 2], 0.f);
    o.w = fmaxf(A1[3] / den1 + bias[64 + cg4 + 3], 0.f);
    *reinterpret_cast<float4*>(&out[(size_t)i * 128 + 64 + cg4]) = o;
  }
}

// ---------------- per-graph pooling, node-parallel ---------------------------
#define SEG_CHUNK 128
__global__ __launch_bounds__(128) void seg_sum_fast(const float* __restrict__ h,
                                                    const int* __restrict__ batch,
                                                    const int* __restrict__ gstart,
                                                    float* __restrict__ reprs) {
  int n0 = blockIdx.x * SEG_CHUNK;
  if (n0 >= NNODES) return;
  int nend = n0 + SEG_CHUNK; if (nend > NNODES) nend = NNODES;
  int tid = threadIdx.x;
  int r = n0;
  while (r < nend) {
    int g = batch[r];
    int segend = gstart[g + 1]; if (segend > nend) segend = nend;
    float a0 = 0.f, a1 = 0.f, a2 = 0.f, a3 = 0.f;
    for (; r + 3 < segend; r += 4) {
      a0 += h[(size_t)r * 128 + tid];
      a1 += h[(size_t)(r + 1) * 128 + tid];
      a2 += h[(size_t)(r + 2) * 128 + tid];
      a3 += h[(size_t)(r + 3) * 128 + tid];
    }
    for (; r < segend; ++r) a0 += h[(size_t)r * 128 + tid];
    atomicAdd(&reprs[g * 128 + tid], (a0 + a1) + (a2 + a3));
  }
}

// ---------------- head MLP + log_softmax -------------------------------------
__global__ __launch_bounds__(128) void head_kernel(const float* __restrict__ reprs,
                                                   const float* __restrict__ pw1,
                                                   const float* __restrict__ pb1,
                                                   const float* __restrict__ pw2,
                                                   const float* __restrict__ pb2,
                                                   float* __restrict__ out) {
  __shared__ float r[128], t1[128], z[NCLS];
  int g = blockIdx.x, tid = threadIdx.x;
  r[tid] = reprs[g * 128 + tid];
  __syncthreads();
  float acc = pb1[tid];
  for (int k = 0; k < 128; ++k) acc = fmaf(r[k], pw1[k * 128 + tid], acc);
  t1[tid] = fmaxf(acc, 0.f);
  __syncthreads();
  if (tid < NCLS) {
    float zz = pb2[tid];
    for (int k = 0; k < 128; ++k) zz = fmaf(t1[k], pw2[k * NCLS + tid], zz);
    z[tid] = zz;
  }
  __syncthreads();
  if (tid == 0) {
    float mx = -1e30f;
    for (int c = 0; c < NCLS; ++c) mx = fmaxf(mx, z[c]);
    float s = 0.f;
    for (int c = 0; c < NCLS; ++c) s += expf(z[c] - mx);
    float ls = logf(s) + mx;
    for (int c = 0; c < NCLS; ++c) out[g * NCLS + c] = z[c] - ls;
  }
}

extern "C" void kernel_launch(void* const* d_in, const int* in_sizes, int n_in,
                              void* d_out, int out_size, void* d_ws, size_t ws_size,
                              hipStream_t stream) {
  const float* x     = (const float*)d_in[0];
  const int*   eidx  = (const int*)d_in[1];
  const int*   batch = (const int*)d_in[2];
  const float* pre_w = (const float*)d_in[3];
  const float* pre_b = (const float*)d_in[4];
  const float* w1    = (const float*)d_in[5];
  const float* asrc1 = (const float*)d_in[6];
  const float* adst1 = (const float*)d_in[7];
  const float* b1    = (const float*)d_in[8];
  const float* w2    = (const float*)d_in[9];
  const float* asrc2 = (const float*)d_in[10];
  const float* adst2 = (const float*)d_in[11];
  const float* b2    = (const float*)d_in[12];
  const float* pw1   = (const float*)d_in[13];
  const float* pb1   = (const float*)d_in[14];
  const float* pw2   = (const float*)d_in[15];
  const float* pb2   = (const float*)d_in[16];
  float* out = (float*)d_out;

  const int* esrc = eidx;
  const int* edst = eidx + NEDGES;

  char* wsp = (char*)d_ws;
  size_t off = 0;
  auto alloc = [&](size_t bytes) -> void* {
    void* p = wsp + off;
    off += (bytes + 255) & ~(size_t)255;
    return p;
  };
  float* h          = (float*)alloc((size_t)NNODES * 128 * 4);
  unsigned int* hwb = (unsigned int*)alloc((size_t)NNODES * 64 * 4);
  float* a_s        = (float*)alloc((size_t)NNODES * 2 * 4);
  float* a_d        = (float*)alloc((size_t)NNODES * 2 * 4);
  float* reprs      = (float*)alloc((size_t)NGRAPH * 128 * 4);
  int* gstart       = (int*)alloc((NGRAPH + 1) * 4);
  int* deg          = (int*)alloc((size_t)NNODES * 4);
  int* incl         = (int*)alloc((size_t)NNODES * 4);
  int* row_ptr      = (int*)alloc(((size_t)NNODES + 1) * 4);
  int* colv         = (int*)alloc((size_t)NEDGES * 4);
  int* blocksum     = (int*)alloc(512 * 4);
  unsigned short* wt_pre = (unsigned short*)alloc((size_t)128 * FIN * 2);
  unsigned short* wt1    = (unsigned short*)alloc((size_t)128 * HDIM * 2);
  unsigned short* wt2    = (unsigned short*)alloc((size_t)128 * HDIM * 2);
  int* blockHist    = (int*)alloc((size_t)EBLK * NBUCK * 4);
  int* blockBaseCol = (int*)alloc((size_t)NBUCK * EBLK * 4);
  int* bucket_total = (int*)alloc(NBUCK * 4);
  int* bucket_ptr   = (int*)alloc((NBUCK + 1) * 4);
  uint2* stagingG   = (uint2*)alloc((size_t)NEDGES * 8);

  int nb = (NNODES + 255) / 256;   // 391
  int wb = NNODES / 4;             // wave-per-node kernels: 256 thr = 4 waves
  int sb = (NNODES + SEG_CHUNK - 1) / SEG_CHUNK;
  int gb = (NNODES + 127) / 128;   // 782 GEMM blocks

  // one-shot weight conversion (bf16, transposed)
  convert_transpose<<<(FIN * 128 + 255) / 256, 256, 0, stream>>>(pre_w, wt_pre, FIN);
  convert_transpose<<<(HDIM * 128 + 255) / 256, 256, 0, stream>>>(w1, wt1, HDIM);
  convert_transpose<<<(HDIM * 128 + 255) / 256, 256, 0, stream>>>(w2, wt2, HDIM);

  // graph boundaries + zeroed pooling accumulator
  hipMemsetAsync(reprs, 0, (size_t)NGRAPH * 128 * 4, stream);
  find_starts<<<1, 256, 0, stream>>>(batch, gstart);

  // bucketed CSR build
  bin_count<<<EBLK, 256, 0, stream>>>(edst, blockHist);
  colscan<<<NBUCK, 512, 0, stream>>>(blockHist, blockBaseCol, bucket_total);
  bscan<<<1, 128, 0, stream>>>(bucket_total, bucket_ptr);
  bin_place<<<EBLK, 512, 0, stream>>>(esrc, edst, blockBaseCol, bucket_ptr, stagingG);
  bucket_deg<<<NBUCK, 1024, 0, stream>>>(stagingG, bucket_ptr, deg);
  scan_block<<<nb, 256, 0, stream>>>(deg, incl, blocksum);
  scan_offsets<<<1, 64, 0, stream>>>(blocksum, nb);
  finalize_csr<<<nb, 256, 0, stream>>>(deg, incl, blocksum, row_ptr);
  bucket_csr<<<NBUCK, 1024, 0, stream>>>(stagingG, bucket_ptr, row_ptr, colv);

  // pre layer: h0 = relu(x @ pre_w + pre_b)
  gemm_mfma<<<gb, 256, 0, stream>>>(x, wt_pre, pre_b, h, nullptr,
                                    nullptr, nullptr, nullptr, nullptr, NNODES, FIN, 1);
  seg_sum_fast<<<sb, 128, 0, stream>>>(h, batch, gstart, reprs);

  // GAT layer 1 (alpha fused into GEMM epilogue)
  gemm_mfma<<<gb, 256, 0, stream>>>(h, wt1, nullptr, nullptr, hwb,
                                    asrc1, adst1, a_s, a_d, NNODES, HDIM, 0);
  aggregate<<<wb, 256, 0, stream>>>(hwb, a_s, a_d, row_ptr, colv, b1, h);
  seg_sum_fast<<<sb, 128, 0, stream>>>(h, batch, gstart, reprs);

  // GAT layer 2
  gemm_mfma<<<gb, 256, 0, stream>>>(h, wt2, nullptr, nullptr, hwb,
                                    asrc2, adst2, a_s, a_d, NNODES, HDIM, 0);
  aggregate<<<wb, 256, 0, stream>>>(hwb, a_s, a_d, row_ptr, colv, b2, h);
  seg_sum_fast<<<sb, 128, 0, stream>>>(h, batch, gstart, reprs);

  // head
  head_kernel<<<NGRAPH, 128, 0, stream>>>(reprs, pw1, pb1, pw2, pb2, out);
}

// Round 9
// 528.246 us; speedup vs baseline: 1.3441x; 1.3441x over previous
//
#include <hip/hip_runtime.h>
#include <hip/hip_bf16.h>
#include <math.h>

#define NNODES 100000
#define NEDGES 1600000
#define FIN 256
#define HDIM 128
#define NGRAPH 128
#define NCLS 10
#define NEG 0.2f

#define NBUCK 98            // buckets of 1024 dst nodes (100000 >> 10 -> 0..97)
#define EPB 4096            // edges per bin_place block
#define EBLK ((NEDGES + EPB - 1) / EPB)   // 391

typedef short bf8 __attribute__((ext_vector_type(8)));
typedef float f4 __attribute__((ext_vector_type(4)));

__device__ __forceinline__ float lrelu(float x) { return x > 0.f ? x : NEG * x; }

__device__ __forceinline__ unsigned short f2bf(float f) {
  union { float f; unsigned int u; } v; v.f = f;
  unsigned int r = v.u + 0x7fffu + ((v.u >> 16) & 1u);   // round-nearest-even
  return (unsigned short)(r >> 16);
}
__device__ __forceinline__ float bf_lo(unsigned int p) {
  union { unsigned int u; float f; } v; v.u = p << 16; return v.f;
}
__device__ __forceinline__ float bf_hi(unsigned int p) {
  union { unsigned int u; float f; } v; v.u = p & 0xffff0000u; return v.f;
}

// ---------------- one-shot weight convert+transpose: w[K][128] -> wt[128][K] -
__global__ __launch_bounds__(256) void convert_transpose(const float* __restrict__ w,
                                                         unsigned short* __restrict__ wt,
                                                         int K) {
  int i = blockIdx.x * 256 + threadIdx.x;
  if (i >= K * 128) return;
  int k = i >> 7, n = i & 127;
  wt[n * K + k] = f2bf(w[(size_t)k * 128 + n]);
}

// ---------------- MFMA GEMM (+ optional fused attention-logit epilogue) ------
__global__ __launch_bounds__(256) void gemm_mfma(const float* __restrict__ A,
                                                 const unsigned short* __restrict__ Bt,
                                                 const float* __restrict__ bias,
                                                 float* __restrict__ C,
                                                 unsigned int* __restrict__ Cp,
                                                 const float* __restrict__ a_src,
                                                 const float* __restrict__ a_dst,
                                                 float* __restrict__ o_as,
                                                 float* __restrict__ o_ad,
                                                 int M, int K, int dorelu) {
  __shared__ bf8 As[512];
  __shared__ bf8 Bs[512];
  int tid = threadIdx.x;
  int wv = tid >> 6, lane = tid & 63;
  int quad = lane >> 4, m16 = lane & 15;
  int row0 = blockIdx.x * 128;

  f4 acc[2][8];
#pragma unroll
  for (int a = 0; a < 2; ++a)
#pragma unroll
    for (int b = 0; b < 8; ++b) acc[a][b] = (f4){0.f, 0.f, 0.f, 0.f};

  for (int kb = 0; kb < K; kb += 32) {
    __syncthreads();
#pragma unroll
    for (int bb = 0; bb < 2; ++bb) {
      int b = tid + bb * 256;
      int l = b & 63, mt = b >> 6;
      int row = row0 + mt * 16 + (l & 15);
      if (row > M - 1) row = M - 1;
      const float* src = &A[(size_t)row * K + kb + (l >> 4) * 8];
      float4 x0 = *reinterpret_cast<const float4*>(src);
      float4 x1 = *reinterpret_cast<const float4*>(src + 4);
      bf8 v;
      v[0] = (short)f2bf(x0.x); v[1] = (short)f2bf(x0.y);
      v[2] = (short)f2bf(x0.z); v[3] = (short)f2bf(x0.w);
      v[4] = (short)f2bf(x1.x); v[5] = (short)f2bf(x1.y);
      v[6] = (short)f2bf(x1.z); v[7] = (short)f2bf(x1.w);
      As[b] = v;
    }
#pragma unroll
    for (int bb = 0; bb < 2; ++bb) {
      int b = tid + bb * 256;
      int l = b & 63, tn = b >> 6;
      int n = tn * 16 + (l & 15);
      Bs[b] = *reinterpret_cast<const bf8*>(&Bt[(size_t)n * K + kb + (l >> 4) * 8]);
    }
    __syncthreads();
    bf8 af0 = As[(wv * 2 + 0) * 64 + lane];
    bf8 af1 = As[(wv * 2 + 1) * 64 + lane];
#pragma unroll
    for (int tn = 0; tn < 8; ++tn) {
      bf8 bfm = Bs[tn * 64 + lane];
      acc[0][tn] = __builtin_amdgcn_mfma_f32_16x16x32_bf16(af0, bfm, acc[0][tn], 0, 0, 0);
      acc[1][tn] = __builtin_amdgcn_mfma_f32_16x16x32_bf16(af1, bfm, acc[1][tn], 0, 0, 0);
    }
  }

  if (Cp) {
    if (a_src) {
      float aS[8], aD[8];
#pragma unroll
      for (int tn = 0; tn < 4; ++tn) {
        aS[tn]     = a_src[tn * 16 + m16];
        aS[tn + 4] = a_src[64 + tn * 16 + m16];
        aD[tn]     = a_dst[tn * 16 + m16];
        aD[tn + 4] = a_dst[64 + tn * 16 + m16];
      }
#pragma unroll
      for (int mt = 0; mt < 2; ++mt)
#pragma unroll
        for (int r = 0; r < 4; ++r) {
          int row = row0 + wv * 32 + mt * 16 + quad * 4 + r;
          float ps0 = 0.f, ps1 = 0.f, pd0 = 0.f, pd1 = 0.f;
#pragma unroll
          for (int tn = 0; tn < 4; ++tn) {
            float v0 = acc[mt][tn][r], v1 = acc[mt][tn + 4][r];
            ps0 = fmaf(v0, aS[tn], ps0);
            ps1 = fmaf(v1, aS[tn + 4], ps1);
            pd0 = fmaf(v0, aD[tn], pd0);
            pd1 = fmaf(v1, aD[tn + 4], pd1);
          }
#pragma unroll
          for (int o = 8; o; o >>= 1) {
            ps0 += __shfl_xor(ps0, o); ps1 += __shfl_xor(ps1, o);
            pd0 += __shfl_xor(pd0, o); pd1 += __shfl_xor(pd1, o);
          }
          if (m16 == 0 && row < M) {
            o_as[2 * row] = ps0; o_as[2 * row + 1] = ps1;
            o_ad[2 * row] = pd0; o_ad[2 * row + 1] = pd1;
          }
        }
    }
#pragma unroll
    for (int mt = 0; mt < 2; ++mt)
#pragma unroll
      for (int tn = 0; tn < 4; ++tn)
#pragma unroll
        for (int r = 0; r < 4; ++r) {
          int row = row0 + wv * 32 + mt * 16 + quad * 4 + r;
          if (row < M) {
            unsigned int p = (unsigned int)f2bf(acc[mt][tn][r]) |
                             ((unsigned int)f2bf(acc[mt][tn + 4][r]) << 16);
            Cp[(size_t)row * 64 + tn * 16 + m16] = p;
          }
        }
  } else {
#pragma unroll
    for (int mt = 0; mt < 2; ++mt)
#pragma unroll
      for (int tn = 0; tn < 8; ++tn) {
        float bv = bias ? bias[tn * 16 + m16] : 0.f;
#pragma unroll
        for (int r = 0; r < 4; ++r) {
          int row = row0 + wv * 32 + mt * 16 + quad * 4 + r;
          if (row < M) {
            float v = acc[mt][tn][r] + bv;
            if (dorelu) v = fmaxf(v, 0.f);
            C[(size_t)row * 128 + tn * 16 + m16] = v;
          }
        }
      }
  }
}

// ---------------- graph boundaries (batch is sorted) -------------------------
__global__ void find_starts(const int* __restrict__ batch, int* __restrict__ gstart) {
  int g = threadIdx.x;
  if (g > NGRAPH) return;
  if (g == NGRAPH) { gstart[g] = NNODES; return; }
  int lo = 0, hi = NNODES;
  while (lo < hi) { int mid = (lo + hi) >> 1; if (batch[mid] < g) lo = mid + 1; else hi = mid; }
  gstart[g] = lo;
}

// ======== CSR build, bucketed two-phase (no random global atomics) ==========
__global__ __launch_bounds__(256) void bin_count(const int* __restrict__ edst,
                                                 int* __restrict__ blockHist) {
  __shared__ int hist[NBUCK];
  int t = threadIdx.x, blk = blockIdx.x;
  if (t < NBUCK) hist[t] = 0;
  __syncthreads();
  int e0 = blk * EPB;
#pragma unroll
  for (int it = 0; it < EPB / 256; ++it) {
    int e = e0 + it * 256 + t;
    if (e < NEDGES) atomicAdd(&hist[((unsigned)edst[e]) >> 10], 1);
  }
  __syncthreads();
  if (t < NBUCK) blockHist[blk * NBUCK + t] = hist[t];
}

__global__ __launch_bounds__(512) void colscan(const int* __restrict__ blockHist,
                                               int* __restrict__ blockBaseCol,
                                               int* __restrict__ bucket_total) {
  __shared__ int s[512];
  int b = blockIdx.x, t = threadIdx.x;
  int v = (t < EBLK) ? blockHist[t * NBUCK + b] : 0;
  s[t] = v;
  __syncthreads();
  for (int off = 1; off < 512; off <<= 1) {
    int u = (t >= off) ? s[t - off] : 0;
    __syncthreads();
    s[t] += u;
    __syncthreads();
  }
  if (t < EBLK) blockBaseCol[b * EBLK + t] = s[t] - v;
  if (t == 511) bucket_total[b] = s[511];
}

__global__ __launch_bounds__(128) void bscan(const int* __restrict__ bucket_total,
                                             int* __restrict__ bucket_ptr) {
  __shared__ int s[128];
  int t = threadIdx.x;
  int v = (t < NBUCK) ? bucket_total[t] : 0;
  s[t] = v;
  __syncthreads();
  for (int off = 1; off < 128; off <<= 1) {
    int u = (t >= off) ? s[t - off] : 0;
    __syncthreads();
    s[t] += u;
    __syncthreads();
  }
  if (t < NBUCK) bucket_ptr[t] = s[t] - v;
  if (t == 127) bucket_ptr[NBUCK] = s[127];
}

__global__ __launch_bounds__(512) void bin_place(const int* __restrict__ esrc,
                                                 const int* __restrict__ edst,
                                                 const int* __restrict__ blockBaseCol,
                                                 const int* __restrict__ bucket_ptr,
                                                 uint2* __restrict__ stagingG) {
  __shared__ int hist[NBUCK + 1], lbase[NBUCK + 1], lcur[NBUCK + 1], cbase[NBUCK];
  __shared__ int tmp[128];
  __shared__ uint2 st[EPB];
  int t = threadIdx.x, blk = blockIdx.x;
  if (t < NBUCK + 1) hist[t] = 0;
  __syncthreads();
  int e0 = blk * EPB;
#pragma unroll
  for (int it = 0; it < EPB / 512; ++it) {
    int e = e0 + it * 512 + t;
    int b = NBUCK;
    if (e < NEDGES) b = ((unsigned)edst[e]) >> 10;
    atomicAdd(&hist[b], 1);
  }
  __syncthreads();
  if (t < 128) tmp[t] = (t < NBUCK + 1) ? hist[t] : 0;
  __syncthreads();
  for (int off = 1; off < 128; off <<= 1) {
    int u = 0;
    if (t < 128 && t >= off) u = tmp[t - off];
    __syncthreads();
    if (t < 128) tmp[t] += u;
    __syncthreads();
  }
  if (t < NBUCK + 1) { int ex = tmp[t] - hist[t]; lbase[t] = ex; lcur[t] = ex; }
  if (t < NBUCK) cbase[t] = bucket_ptr[t] + blockBaseCol[t * EBLK + blk];
  __syncthreads();
#pragma unroll
  for (int it = 0; it < EPB / 512; ++it) {
    int e = e0 + it * 512 + t;
    unsigned s = 0, d = 0xFFFFFFFFu;
    if (e < NEDGES) { s = (unsigned)esrc[e]; d = (unsigned)edst[e]; }
    int b = (d == 0xFFFFFFFFu) ? NBUCK : (int)(d >> 10);
    int slot = atomicAdd(&lcur[b], 1);
    st[slot] = make_uint2(s, d);
  }
  __syncthreads();
  for (int i = t; i < EPB; i += 512) {
    uint2 ed = st[i];
    if (ed.y == 0xFFFFFFFFu) continue;
    int b = (int)(ed.y >> 10);
    stagingG[cbase[b] + (i - lbase[b])] = ed;
  }
}

// per-bucket degree histogram + LDS scan -> row_ptr directly (replaces
// scan_block / serial scan_offsets / finalize_csr: row_ptr[n] =
// bucket_ptr[b] + excl-scan of bucket-local degrees)
__global__ __launch_bounds__(1024) void bucket_deg_scan(const uint2* __restrict__ stagingG,
                                                        const int* __restrict__ bucket_ptr,
                                                        int* __restrict__ row_ptr) {
  __shared__ int dl[1024];
  int b = blockIdx.x, t = threadIdx.x;
  dl[t] = 0;
  __syncthreads();
  int s0 = bucket_ptr[b], s1 = bucket_ptr[b + 1];
  for (int j = s0 + t; j < s1; j += 1024)
    atomicAdd(&dl[stagingG[j].y & 1023], 1);
  __syncthreads();
  int myDeg = dl[t];
  for (int off = 1; off < 1024; off <<= 1) {
    int u = (t >= off) ? dl[t - off] : 0;
    __syncthreads();
    dl[t] += u;
    __syncthreads();
  }
  int excl = dl[t] - myDeg;
  int n = (b << 10) + t;
  if (n < NNODES) row_ptr[n] = s0 + excl;
  if (n == NNODES - 1) row_ptr[NNODES] = s0 + excl + myDeg;
}

__global__ __launch_bounds__(1024) void bucket_csr(const uint2* __restrict__ stagingG,
                                                   const int* __restrict__ bucket_ptr,
                                                   const int* __restrict__ row_ptr,
                                                   int* __restrict__ colv) {
  __shared__ int cur[1024];
  int b = blockIdx.x, t = threadIdx.x;
  int n = (b << 10) + t;
  cur[t] = (n < NNODES) ? row_ptr[n] : 0;
  __syncthreads();
  int s0 = bucket_ptr[b], s1 = bucket_ptr[b + 1];
  for (int j = s0 + t; j < s1; j += 1024) {
    uint2 e = stagingG[j];
    int pos = atomicAdd(&cur[e.y & 1023], 1);
    colv[pos] = (int)e.x;
  }
}

// ---------------- tiered gather: compile-time lane idx -> readlane/SGPR ------
template<int T>
__device__ __forceinline__ void gather_T(const unsigned int* __restrict__ hwb,
                                         int lane, int sl, float w0l, float w1l,
                                         float& acc0, float& acc1) {
#pragma unroll
  for (int t = 0; t < T; ++t) {
    int s = __builtin_amdgcn_readlane(sl, t);                                   // SGPR
    float w0 = __uint_as_float(__builtin_amdgcn_readlane(__float_as_uint(w0l), t));
    float w1 = __uint_as_float(__builtin_amdgcn_readlane(__float_as_uint(w1l), t));
    unsigned q = hwb[(size_t)s * 64 + lane];   // saddr + lane offset
    acc0 = fmaf(w0, bf_lo(q), acc0);
    acc1 = fmaf(w1, bf_hi(q), acc1);
  }
}

// ---------------- softmax aggregation: one wave per dst node -----------------
__global__ __launch_bounds__(256) void aggregate(const unsigned int* __restrict__ hwb,
                                                 const float* __restrict__ a_s,
                                                 const float* __restrict__ a_d,
                                                 const int* __restrict__ row_ptr,
                                                 const int* __restrict__ colv,
                                                 const float* __restrict__ bias,
                                                 float* __restrict__ out) {
  int i = (blockIdx.x * 256 + threadIdx.x) >> 6;
  int lane = threadIdx.x & 63;
  if (i >= NNODES) return;
  float ad0 = a_d[2 * i], ad1 = a_d[2 * i + 1];
  float es0 = lrelu(a_s[2 * i] + ad0), es1 = lrelu(a_s[2 * i + 1] + ad1);  // self edge
  int start = row_ptr[i], end = row_ptr[i + 1];
  int deg = end - start;

  int sl = 0; float e0l = -1e30f, e1l = -1e30f;
  if (lane < deg) {
    sl = colv[start + lane];
    float2 av = *reinterpret_cast<const float2*>(&a_s[2 * sl]);
    e0l = lrelu(av.x + ad0); e1l = lrelu(av.y + ad1);
  }
  float m0 = fmaxf(es0, e0l), m1 = fmaxf(es1, e1l);
  for (int j = start + 64 + lane; j < end; j += 64) {
    int s = colv[j];
    float2 av = *reinterpret_cast<const float2*>(&a_s[2 * s]);
    m0 = fmaxf(m0, lrelu(av.x + ad0));
    m1 = fmaxf(m1, lrelu(av.y + ad1));
  }
  for (int o = 32; o; o >>= 1) {
    m0 = fmaxf(m0, __shfl_xor(m0, o));
    m1 = fmaxf(m1, __shfl_xor(m1, o));
  }
  float w0l = lane < deg ? __expf(e0l - m0) : 0.f;
  float w1l = lane < deg ? __expf(e1l - m1) : 0.f;
  float d0 = w0l, d1 = w1l;
  for (int o = 32; o; o >>= 1) { d0 += __shfl_xor(d0, o); d1 += __shfl_xor(d1, o); }
  float ws0 = __expf(es0 - m0), ws1 = __expf(es1 - m1);
  float den0 = d0 + ws0, den1 = d1 + ws1;

  unsigned int ps = hwb[(size_t)i * 64 + lane];
  float acc0 = ws0 * bf_lo(ps), acc1 = ws1 * bf_hi(ps);
  int dmin = deg < 64 ? deg : 64;
  // tiered fully-unrolled gather; ghost lanes carry sl=0, w=0 (hwb[0] is L1-hot)
  switch ((dmin + 7) >> 3) {
    case 1: gather_T<8 >(hwb, lane, sl, w0l, w1l, acc0, acc1); break;
    case 2: gather_T<16>(hwb, lane, sl, w0l, w1l, acc0, acc1); break;
    case 3: gather_T<24>(hwb, lane, sl, w0l, w1l, acc0, acc1); break;
    case 4: gather_T<32>(hwb, lane, sl, w0l, w1l, acc0, acc1); break;
    case 5: gather_T<40>(hwb, lane, sl, w0l, w1l, acc0, acc1); break;
    case 6: gather_T<48>(hwb, lane, sl, w0l, w1l, acc0, acc1); break;
    case 7: gather_T<56>(hwb, lane, sl, w0l, w1l, acc0, acc1); break;
    case 8: gather_T<64>(hwb, lane, sl, w0l, w1l, acc0, acc1); break;
    default: break;
  }
  for (int j = start + 64; j < end; ++j) {   // rare overflow path (deg > 64)
    int s = colv[j];
    float2 av = *reinterpret_cast<const float2*>(&a_s[2 * s]);
    float w0 = __expf(lrelu(av.x + ad0) - m0);
    float w1 = __expf(lrelu(av.y + ad1) - m1);
    den0 += w0; den1 += w1;
    unsigned int q = hwb[(size_t)s * 64 + lane];
    acc0 = fmaf(w0, bf_lo(q), acc0);
    acc1 = fmaf(w1, bf_hi(q), acc1);
  }
  out[(size_t)i * 128 + lane]      = fmaxf(acc0 / den0 + bias[lane], 0.f);
  out[(size_t)i * 128 + 64 + lane] = fmaxf(acc1 / den1 + bias[64 + lane], 0.f);
}

// ---------------- per-graph pooling, node-parallel ---------------------------
#define SEG_CHUNK 128
__global__ __launch_bounds__(128) void seg_sum_fast(const float* __restrict__ h,
                                                    const int* __restrict__ batch,
                                                    const int* __restrict__ gstart,
                                                    float* __restrict__ reprs) {
  int n0 = blockIdx.x * SEG_CHUNK;
  if (n0 >= NNODES) return;
  int nend = n0 + SEG_CHUNK; if (nend > NNODES) nend = NNODES;
  int tid = threadIdx.x;
  int r = n0;
  while (r < nend) {
    int g = batch[r];
    int segend = gstart[g + 1]; if (segend > nend) segend = nend;
    float a0 = 0.f, a1 = 0.f, a2 = 0.f, a3 = 0.f;
    for (; r + 3 < segend; r += 4) {
      a0 += h[(size_t)r * 128 + tid];
      a1 += h[(size_t)(r + 1) * 128 + tid];
      a2 += h[(size_t)(r + 2) * 128 + tid];
      a3 += h[(size_t)(r + 3) * 128 + tid];
    }
    for (; r < segend; ++r) a0 += h[(size_t)r * 128 + tid];
    atomicAdd(&reprs[g * 128 + tid], (a0 + a1) + (a2 + a3));
  }
}

// ---------------- head MLP + log_softmax -------------------------------------
__global__ __launch_bounds__(128) void head_kernel(const float* __restrict__ reprs,
                                                   const float* __restrict__ pw1,
                                                   const float* __restrict__ pb1,
                                                   const float* __restrict__ pw2,
                                                   const float* __restrict__ pb2,
                                                   float* __restrict__ out) {
  __shared__ float r[128], t1[128], z[NCLS];
  int g = blockIdx.x, tid = threadIdx.x;
  r[tid] = reprs[g * 128 + tid];
  __syncthreads();
  float acc = pb1[tid];
  for (int k = 0; k < 128; ++k) acc = fmaf(r[k], pw1[k * 128 + tid], acc);
  t1[tid] = fmaxf(acc, 0.f);
  __syncthreads();
  if (tid < NCLS) {
    float zz = pb2[tid];
    for (int k = 0; k < 128; ++k) zz = fmaf(t1[k], pw2[k * NCLS + tid], zz);
    z[tid] = zz;
  }
  __syncthreads();
  if (tid == 0) {
    float mx = -1e30f;
    for (int c = 0; c < NCLS; ++c) mx = fmaxf(mx, z[c]);
    float s = 0.f;
    for (int c = 0; c < NCLS; ++c) s += expf(z[c] - mx);
    float ls = logf(s) + mx;
    for (int c = 0; c < NCLS; ++c) out[g * NCLS + c] = z[c] - ls;
  }
}

extern "C" void kernel_launch(void* const* d_in, const int* in_sizes, int n_in,
                              void* d_out, int out_size, void* d_ws, size_t ws_size,
                              hipStream_t stream) {
  const float* x     = (const float*)d_in[0];
  const int*   eidx  = (const int*)d_in[1];
  const int*   batch = (const int*)d_in[2];
  const float* pre_w = (const float*)d_in[3];
  const float* pre_b = (const float*)d_in[4];
  const float* w1    = (const float*)d_in[5];
  const float* asrc1 = (const float*)d_in[6];
  const float* adst1 = (const float*)d_in[7];
  const float* b1    = (const float*)d_in[8];
  const float* w2    = (const float*)d_in[9];
  const float* asrc2 = (const float*)d_in[10];
  const float* adst2 = (const float*)d_in[11];
  const float* b2    = (const float*)d_in[12];
  const float* pw1   = (const float*)d_in[13];
  const float* pb1   = (const float*)d_in[14];
  const float* pw2   = (const float*)d_in[15];
  const float* pb2   = (const float*)d_in[16];
  float* out = (float*)d_out;

  const int* esrc = eidx;
  const int* edst = eidx + NEDGES;

  char* wsp = (char*)d_ws;
  size_t off = 0;
  auto alloc = [&](size_t bytes) -> void* {
    void* p = wsp + off;
    off += (bytes + 255) & ~(size_t)255;
    return p;
  };
  float* h          = (float*)alloc((size_t)NNODES * 128 * 4);
  unsigned int* hwb = (unsigned int*)alloc((size_t)NNODES * 64 * 4);
  float* a_s        = (float*)alloc((size_t)NNODES * 2 * 4);
  float* a_d        = (float*)alloc((size_t)NNODES * 2 * 4);
  float* reprs      = (float*)alloc((size_t)NGRAPH * 128 * 4);
  int* gstart       = (int*)alloc((NGRAPH + 1) * 4);
  int* row_ptr      = (int*)alloc(((size_t)NNODES + 1) * 4);
  int* colv         = (int*)alloc((size_t)NEDGES * 4);
  unsigned short* wt_pre = (unsigned short*)alloc((size_t)128 * FIN * 2);
  unsigned short* wt1    = (unsigned short*)alloc((size_t)128 * HDIM * 2);
  unsigned short* wt2    = (unsigned short*)alloc((size_t)128 * HDIM * 2);
  int* blockHist    = (int*)alloc((size_t)EBLK * NBUCK * 4);
  int* blockBaseCol = (int*)alloc((size_t)NBUCK * EBLK * 4);
  int* bucket_total = (int*)alloc(NBUCK * 4);
  int* bucket_ptr   = (int*)alloc((NBUCK + 1) * 4);
  uint2* stagingG   = (uint2*)alloc((size_t)NEDGES * 8);

  int wb = NNODES / 4;             // wave-per-node kernels: 256 thr = 4 waves
  int sb = (NNODES + SEG_CHUNK - 1) / SEG_CHUNK;
  int gb = (NNODES + 127) / 128;   // 782 GEMM blocks

  // one-shot weight conversion (bf16, transposed)
  convert_transpose<<<(FIN * 128 + 255) / 256, 256, 0, stream>>>(pre_w, wt_pre, FIN);
  convert_transpose<<<(HDIM * 128 + 255) / 256, 256, 0, stream>>>(w1, wt1, HDIM);
  convert_transpose<<<(HDIM * 128 + 255) / 256, 256, 0, stream>>>(w2, wt2, HDIM);

  // graph boundaries + zeroed pooling accumulator
  hipMemsetAsync(reprs, 0, (size_t)NGRAPH * 128 * 4, stream);
  find_starts<<<1, 256, 0, stream>>>(batch, gstart);

  // bucketed CSR build (row_ptr via per-bucket LDS scan — no serial kernel)
  bin_count<<<EBLK, 256, 0, stream>>>(edst, blockHist);
  colscan<<<NBUCK, 512, 0, stream>>>(blockHist, blockBaseCol, bucket_total);
  bscan<<<1, 128, 0, stream>>>(bucket_total, bucket_ptr);
  bin_place<<<EBLK, 512, 0, stream>>>(esrc, edst, blockBaseCol, bucket_ptr, stagingG);
  bucket_deg_scan<<<NBUCK, 1024, 0, stream>>>(stagingG, bucket_ptr, row_ptr);
  bucket_csr<<<NBUCK, 1024, 0, stream>>>(stagingG, bucket_ptr, row_ptr, colv);

  // pre layer: h0 = relu(x @ pre_w + pre_b)
  gemm_mfma<<<gb, 256, 0, stream>>>(x, wt_pre, pre_b, h, nullptr,
                                    nullptr, nullptr, nullptr, nullptr, NNODES, FIN, 1);
  seg_sum_fast<<<sb, 128, 0, stream>>>(h, batch, gstart, reprs);

  // GAT layer 1 (alpha fused into GEMM epilogue)
  gemm_mfma<<<gb, 256, 0, stream>>>(h, wt1, nullptr, nullptr, hwb,
                                    asrc1, adst1, a_s, a_d, NNODES, HDIM, 0);
  aggregate<<<wb, 256, 0, stream>>>(hwb, a_s, a_d, row_ptr, colv, b1, h);
  seg_sum_fast<<<sb, 128, 0, stream>>>(h, batch, gstart, reprs);

  // GAT layer 2
  gemm_mfma<<<gb, 256, 0, stream>>>(h, wt2, nullptr, nullptr, hwb,
                                    asrc2, adst2, a_s, a_d, NNODES, HDIM, 0);
  aggregate<<<wb, 256, 0, stream>>>(hwb, a_s, a_d, row_ptr, colv, b2, h);
  seg_sum_fast<<<sb, 128, 0, stream>>>(h, batch, gstart, reprs);

  // head
  head_kernel<<<NGRAPH, 128, 0, stream>>>(reprs, pw1, pb1, pw2, pb2, out);
}

// Round 10
// 513.169 us; speedup vs baseline: 1.3836x; 1.0294x over previous
//
#include <hip/hip_runtime.h>
#include <hip/hip_bf16.h>
#include <math.h>

#define NNODES 100000
#define NEDGES 1600000
#define FIN 256
#define HDIM 128
#define NGRAPH 128
#define NCLS 10
#define NEG 0.2f

#define NBUCK 98            // buckets of 1024 dst nodes
#define EPB 4096            // edges per bin_place block
#define EBLK ((NEDGES + EPB - 1) / EPB)   // 391

typedef short bf8 __attribute__((ext_vector_type(8)));
typedef float f4 __attribute__((ext_vector_type(4)));

__device__ __forceinline__ float lrelu(float x) { return x > 0.f ? x : NEG * x; }

__device__ __forceinline__ unsigned short f2bf(float f) {
  union { float f; unsigned int u; } v; v.f = f;
  unsigned int r = v.u + 0x7fffu + ((v.u >> 16) & 1u);   // round-nearest-even
  return (unsigned short)(r >> 16);
}
__device__ __forceinline__ float bf2f(unsigned short u) {
  union { unsigned int u; float f; } v; v.u = ((unsigned int)u) << 16; return v.f;
}
__device__ __forceinline__ float bf_lo(unsigned int p) {
  union { unsigned int u; float f; } v; v.u = p << 16; return v.f;
}
__device__ __forceinline__ float bf_hi(unsigned int p) {
  union { unsigned int u; float f; } v; v.u = p & 0xffff0000u; return v.f;
}

// ---------------- one-shot weight convert+transpose: w[K][128] -> wt[128][K] -
__global__ __launch_bounds__(256) void convert_transpose(const float* __restrict__ w,
                                                         unsigned short* __restrict__ wt,
                                                         int K) {
  int i = blockIdx.x * 256 + threadIdx.x;
  if (i >= K * 128) return;
  int k = i >> 7, n = i & 127;
  wt[n * K + k] = f2bf(w[(size_t)k * 128 + n]);
}

// ---------------- MFMA GEMM (+ optional fused attention-logit epilogue) ------
// A: fp32 (a_bf16=0) or bf16 row-major (a_bf16=1).
// Output: Cb (bf16 h, +bias+relu) OR Cp (packed ushort2{h0,h1}) + fused logits.
__global__ __launch_bounds__(256) void gemm_mfma(const void* __restrict__ Av,
                                                 int a_bf16,
                                                 const unsigned short* __restrict__ Bt,
                                                 const float* __restrict__ bias,
                                                 unsigned short* __restrict__ Cb,
                                                 unsigned int* __restrict__ Cp,
                                                 const float* __restrict__ a_src,
                                                 const float* __restrict__ a_dst,
                                                 float* __restrict__ o_as,
                                                 float* __restrict__ o_ad,
                                                 int M, int K, int dorelu) {
  __shared__ bf8 As[512];
  __shared__ bf8 Bs[512];
  int tid = threadIdx.x;
  int wv = tid >> 6, lane = tid & 63;
  int quad = lane >> 4, m16 = lane & 15;
  int row0 = blockIdx.x * 128;

  f4 acc[2][8];
#pragma unroll
  for (int a = 0; a < 2; ++a)
#pragma unroll
    for (int b = 0; b < 8; ++b) acc[a][b] = (f4){0.f, 0.f, 0.f, 0.f};

  for (int kb = 0; kb < K; kb += 32) {
    __syncthreads();
#pragma unroll
    for (int bb = 0; bb < 2; ++bb) {
      int b = tid + bb * 256;
      int l = b & 63, mt = b >> 6;
      int row = row0 + mt * 16 + (l & 15);
      if (row > M - 1) row = M - 1;
      if (a_bf16) {
        const unsigned short* src =
            (const unsigned short*)Av + (size_t)row * K + kb + (l >> 4) * 8;
        As[b] = *reinterpret_cast<const bf8*>(src);
      } else {
        const float* src = (const float*)Av + (size_t)row * K + kb + (l >> 4) * 8;
        float4 x0 = *reinterpret_cast<const float4*>(src);
        float4 x1 = *reinterpret_cast<const float4*>(src + 4);
        bf8 v;
        v[0] = (short)f2bf(x0.x); v[1] = (short)f2bf(x0.y);
        v[2] = (short)f2bf(x0.z); v[3] = (short)f2bf(x0.w);
        v[4] = (short)f2bf(x1.x); v[5] = (short)f2bf(x1.y);
        v[6] = (short)f2bf(x1.z); v[7] = (short)f2bf(x1.w);
        As[b] = v;
      }
    }
#pragma unroll
    for (int bb = 0; bb < 2; ++bb) {
      int b = tid + bb * 256;
      int l = b & 63, tn = b >> 6;
      int n = tn * 16 + (l & 15);
      Bs[b] = *reinterpret_cast<const bf8*>(&Bt[(size_t)n * K + kb + (l >> 4) * 8]);
    }
    __syncthreads();
    bf8 af0 = As[(wv * 2 + 0) * 64 + lane];
    bf8 af1 = As[(wv * 2 + 1) * 64 + lane];
#pragma unroll
    for (int tn = 0; tn < 8; ++tn) {
      bf8 bfm = Bs[tn * 64 + lane];
      acc[0][tn] = __builtin_amdgcn_mfma_f32_16x16x32_bf16(af0, bfm, acc[0][tn], 0, 0, 0);
      acc[1][tn] = __builtin_amdgcn_mfma_f32_16x16x32_bf16(af1, bfm, acc[1][tn], 0, 0, 0);
    }
  }

  if (Cp) {
    if (a_src) {
      float aS[8], aD[8];
#pragma unroll
      for (int tn = 0; tn < 4; ++tn) {
        aS[tn]     = a_src[tn * 16 + m16];
        aS[tn + 4] = a_src[64 + tn * 16 + m16];
        aD[tn]     = a_dst[tn * 16 + m16];
        aD[tn + 4] = a_dst[64 + tn * 16 + m16];
      }
#pragma unroll
      for (int mt = 0; mt < 2; ++mt)
#pragma unroll
        for (int r = 0; r < 4; ++r) {
          int row = row0 + wv * 32 + mt * 16 + quad * 4 + r;
          float ps0 = 0.f, ps1 = 0.f, pd0 = 0.f, pd1 = 0.f;
#pragma unroll
          for (int tn = 0; tn < 4; ++tn) {
            float v0 = acc[mt][tn][r], v1 = acc[mt][tn + 4][r];
            ps0 = fmaf(v0, aS[tn], ps0);
            ps1 = fmaf(v1, aS[tn + 4], ps1);
            pd0 = fmaf(v0, aD[tn], pd0);
            pd1 = fmaf(v1, aD[tn + 4], pd1);
          }
#pragma unroll
          for (int o = 8; o; o >>= 1) {
            ps0 += __shfl_xor(ps0, o); ps1 += __shfl_xor(ps1, o);
            pd0 += __shfl_xor(pd0, o); pd1 += __shfl_xor(pd1, o);
          }
          if (m16 == 0 && row < M) {
            o_as[2 * row] = ps0; o_as[2 * row + 1] = ps1;
            o_ad[2 * row] = pd0; o_ad[2 * row + 1] = pd1;
          }
        }
    }
#pragma unroll
    for (int mt = 0; mt < 2; ++mt)
#pragma unroll
      for (int tn = 0; tn < 4; ++tn)
#pragma unroll
        for (int r = 0; r < 4; ++r) {
          int row = row0 + wv * 32 + mt * 16 + quad * 4 + r;
          if (row < M) {
            unsigned int p = (unsigned int)f2bf(acc[mt][tn][r]) |
                             ((unsigned int)f2bf(acc[mt][tn + 4][r]) << 16);
            Cp[(size_t)row * 64 + tn * 16 + m16] = p;
          }
        }
  } else {
#pragma unroll
    for (int mt = 0; mt < 2; ++mt)
#pragma unroll
      for (int tn = 0; tn < 8; ++tn) {
        float bv = bias ? bias[tn * 16 + m16] : 0.f;
#pragma unroll
        for (int r = 0; r < 4; ++r) {
          int row = row0 + wv * 32 + mt * 16 + quad * 4 + r;
          if (row < M) {
            float v = acc[mt][tn][r] + bv;
            if (dorelu) v = fmaxf(v, 0.f);
            Cb[(size_t)row * 128 + tn * 16 + m16] = f2bf(v);
          }
        }
      }
  }
}

// ---------------- graph boundaries (batch is sorted) -------------------------
__global__ void find_starts(const int* __restrict__ batch, int* __restrict__ gstart) {
  int g = threadIdx.x;
  if (g > NGRAPH) return;
  if (g == NGRAPH) { gstart[g] = NNODES; return; }
  int lo = 0, hi = NNODES;
  while (lo < hi) { int mid = (lo + hi) >> 1; if (batch[mid] < g) lo = mid + 1; else hi = mid; }
  gstart[g] = lo;
}

// ======== CSR build, bucketed two-phase (no random global atomics) ==========
__global__ __launch_bounds__(256) void bin_count(const int* __restrict__ edst,
                                                 int* __restrict__ blockHist) {
  __shared__ int hist[NBUCK];
  int t = threadIdx.x, blk = blockIdx.x;
  if (t < NBUCK) hist[t] = 0;
  __syncthreads();
  int e0 = blk * EPB;
#pragma unroll
  for (int it = 0; it < EPB / 256; ++it) {
    int e = e0 + it * 256 + t;
    if (e < NEDGES) atomicAdd(&hist[((unsigned)edst[e]) >> 10], 1);
  }
  __syncthreads();
  if (t < NBUCK) blockHist[blk * NBUCK + t] = hist[t];
}

__global__ __launch_bounds__(512) void colscan(const int* __restrict__ blockHist,
                                               int* __restrict__ blockBaseCol,
                                               int* __restrict__ bucket_total) {
  __shared__ int s[512];
  int b = blockIdx.x, t = threadIdx.x;
  int v = (t < EBLK) ? blockHist[t * NBUCK + b] : 0;
  s[t] = v;
  __syncthreads();
  for (int off = 1; off < 512; off <<= 1) {
    int u = (t >= off) ? s[t - off] : 0;
    __syncthreads();
    s[t] += u;
    __syncthreads();
  }
  if (t < EBLK) blockBaseCol[b * EBLK + t] = s[t] - v;
  if (t == 511) bucket_total[b] = s[511];
}

__global__ __launch_bounds__(128) void bscan(const int* __restrict__ bucket_total,
                                             int* __restrict__ bucket_ptr) {
  __shared__ int s[128];
  int t = threadIdx.x;
  int v = (t < NBUCK) ? bucket_total[t] : 0;
  s[t] = v;
  __syncthreads();
  for (int off = 1; off < 128; off <<= 1) {
    int u = (t >= off) ? s[t - off] : 0;
    __syncthreads();
    s[t] += u;
    __syncthreads();
  }
  if (t < NBUCK) bucket_ptr[t] = s[t] - v;
  if (t == 127) bucket_ptr[NBUCK] = s[127];
}

// staging entry: (dst_local_10bits << 17) | src_17bits  (NNODES < 2^17)
__global__ __launch_bounds__(512) void bin_place(const int* __restrict__ esrc,
                                                 const int* __restrict__ edst,
                                                 const int* __restrict__ blockBaseCol,
                                                 const int* __restrict__ bucket_ptr,
                                                 unsigned* __restrict__ stagingG) {
  __shared__ int hist[NBUCK + 1], lbase[NBUCK + 1], lcur[NBUCK + 1], cbase[NBUCK];
  __shared__ int tmp[128];
  __shared__ uint2 st[EPB];
  int t = threadIdx.x, blk = blockIdx.x;
  if (t < NBUCK + 1) hist[t] = 0;
  __syncthreads();
  int e0 = blk * EPB;
#pragma unroll
  for (int it = 0; it < EPB / 512; ++it) {
    int e = e0 + it * 512 + t;
    int b = NBUCK;
    if (e < NEDGES) b = ((unsigned)edst[e]) >> 10;
    atomicAdd(&hist[b], 1);
  }
  __syncthreads();
  if (t < 128) tmp[t] = (t < NBUCK + 1) ? hist[t] : 0;
  __syncthreads();
  for (int off = 1; off < 128; off <<= 1) {
    int u = 0;
    if (t < 128 && t >= off) u = tmp[t - off];
    __syncthreads();
    if (t < 128) tmp[t] += u;
    __syncthreads();
  }
  if (t < NBUCK + 1) { int ex = tmp[t] - hist[t]; lbase[t] = ex; lcur[t] = ex; }
  if (t < NBUCK) cbase[t] = bucket_ptr[t] + blockBaseCol[t * EBLK + blk];
  __syncthreads();
#pragma unroll
  for (int it = 0; it < EPB / 512; ++it) {
    int e = e0 + it * 512 + t;
    unsigned s = 0, d = 0xFFFFFFFFu;
    if (e < NEDGES) { s = (unsigned)esrc[e]; d = (unsigned)edst[e]; }
    int b = (d == 0xFFFFFFFFu) ? NBUCK : (int)(d >> 10);
    int slot = atomicAdd(&lcur[b], 1);
    st[slot] = make_uint2(s, d);
  }
  __syncthreads();
  for (int i = t; i < EPB; i += 512) {
    uint2 ed = st[i];
    if (ed.y == 0xFFFFFFFFu) continue;
    int b = (int)(ed.y >> 10);
    stagingG[cbase[b] + (i - lbase[b])] = ((ed.y & 1023u) << 17) | ed.x;
  }
}

// fused: per-bucket degree histogram + LDS scan -> row_ptr, then scatter
// (second staging read is L2-hot; scatter confined to L2-resident window)
__global__ __launch_bounds__(1024) void bucket_csr_fused(const unsigned* __restrict__ stagingG,
                                                         const int* __restrict__ bucket_ptr,
                                                         int* __restrict__ row_ptr,
                                                         int* __restrict__ colv) {
  __shared__ int dl[1024];
  __shared__ int cur[1024];
  int b = blockIdx.x, t = threadIdx.x;
  dl[t] = 0;
  __syncthreads();
  int s0 = bucket_ptr[b], s1 = bucket_ptr[b + 1];
  for (int j = s0 + t; j < s1; j += 1024)
    atomicAdd(&dl[stagingG[j] >> 17], 1);
  __syncthreads();
  int myDeg = dl[t];
  for (int off = 1; off < 1024; off <<= 1) {
    int u = (t >= off) ? dl[t - off] : 0;
    __syncthreads();
    dl[t] += u;
    __syncthreads();
  }
  int rp = s0 + dl[t] - myDeg;
  cur[t] = rp;
  int n = (b << 10) + t;
  if (n < NNODES) row_ptr[n] = rp;
  if (n == NNODES - 1) row_ptr[NNODES] = rp + myDeg;
  __syncthreads();
  for (int j = s0 + t; j < s1; j += 1024) {
    unsigned v = stagingG[j];
    int pos = atomicAdd(&cur[v >> 17], 1);
    colv[pos] = (int)(v & 0x1FFFFu);
  }
}

// ---------------- tiered gather: compile-time lane idx -> readlane/SGPR ------
template<int T>
__device__ __forceinline__ void gather_T(const unsigned int* __restrict__ hwb,
                                         int lane, int sl, float w0l, float w1l,
                                         float& acc0, float& acc1) {
#pragma unroll
  for (int t = 0; t < T; ++t) {
    int s = __builtin_amdgcn_readlane(sl, t);                                   // SGPR
    float w0 = __uint_as_float(__builtin_amdgcn_readlane(__float_as_uint(w0l), t));
    float w1 = __uint_as_float(__builtin_amdgcn_readlane(__float_as_uint(w1l), t));
    unsigned q = hwb[(size_t)s * 64 + lane];   // saddr + lane offset
    acc0 = fmaf(w0, bf_lo(q), acc0);
    acc1 = fmaf(w1, bf_hi(q), acc1);
  }
}

// ---------------- softmax aggregation: one wave per dst node -----------------
// out: bf16 h, row-major [N][128]
__global__ __launch_bounds__(256) void aggregate(const unsigned int* __restrict__ hwb,
                                                 const float* __restrict__ a_s,
                                                 const float* __restrict__ a_d,
                                                 const int* __restrict__ row_ptr,
                                                 const int* __restrict__ colv,
                                                 const float* __restrict__ bias,
                                                 unsigned short* __restrict__ out) {
  int i = (blockIdx.x * 256 + threadIdx.x) >> 6;
  int lane = threadIdx.x & 63;
  if (i >= NNODES) return;
  float ad0 = a_d[2 * i], ad1 = a_d[2 * i + 1];
  float es0 = lrelu(a_s[2 * i] + ad0), es1 = lrelu(a_s[2 * i + 1] + ad1);  // self edge
  int start = row_ptr[i], end = row_ptr[i + 1];
  int deg = end - start;

  int sl = 0; float e0l = -1e30f, e1l = -1e30f;
  if (lane < deg) {
    sl = colv[start + lane];
    float2 av = *reinterpret_cast<const float2*>(&a_s[2 * sl]);
    e0l = lrelu(av.x + ad0); e1l = lrelu(av.y + ad1);
  }
  float m0 = fmaxf(es0, e0l), m1 = fmaxf(es1, e1l);
  for (int j = start + 64 + lane; j < end; j += 64) {
    int s = colv[j];
    float2 av = *reinterpret_cast<const float2*>(&a_s[2 * s]);
    m0 = fmaxf(m0, lrelu(av.x + ad0));
    m1 = fmaxf(m1, lrelu(av.y + ad1));
  }
  for (int o = 32; o; o >>= 1) {
    m0 = fmaxf(m0, __shfl_xor(m0, o));
    m1 = fmaxf(m1, __shfl_xor(m1, o));
  }
  float w0l = lane < deg ? __expf(e0l - m0) : 0.f;
  float w1l = lane < deg ? __expf(e1l - m1) : 0.f;
  float d0 = w0l, d1 = w1l;
  for (int o = 32; o; o >>= 1) { d0 += __shfl_xor(d0, o); d1 += __shfl_xor(d1, o); }
  float ws0 = __expf(es0 - m0), ws1 = __expf(es1 - m1);
  float den0 = d0 + ws0, den1 = d1 + ws1;

  unsigned int ps = hwb[(size_t)i * 64 + lane];
  float acc0 = ws0 * bf_lo(ps), acc1 = ws1 * bf_hi(ps);
  int dmin = deg < 64 ? deg : 64;
  // tiered fully-unrolled gather; ghost lanes carry sl=0, w=0 (hwb[0] is L1-hot)
  switch ((dmin + 7) >> 3) {
    case 1: gather_T<8 >(hwb, lane, sl, w0l, w1l, acc0, acc1); break;
    case 2: gather_T<16>(hwb, lane, sl, w0l, w1l, acc0, acc1); break;
    case 3: gather_T<24>(hwb, lane, sl, w0l, w1l, acc0, acc1); break;
    case 4: gather_T<32>(hwb, lane, sl, w0l, w1l, acc0, acc1); break;
    case 5: gather_T<40>(hwb, lane, sl, w0l, w1l, acc0, acc1); break;
    case 6: gather_T<48>(hwb, lane, sl, w0l, w1l, acc0, acc1); break;
    case 7: gather_T<56>(hwb, lane, sl, w0l, w1l, acc0, acc1); break;
    case 8: gather_T<64>(hwb, lane, sl, w0l, w1l, acc0, acc1); break;
    default: break;
  }
  for (int j = start + 64; j < end; ++j) {   // rare overflow path (deg > 64)
    int s = colv[j];
    float2 av = *reinterpret_cast<const float2*>(&a_s[2 * s]);
    float w0 = __expf(lrelu(av.x + ad0) - m0);
    float w1 = __expf(lrelu(av.y + ad1) - m1);
    den0 += w0; den1 += w1;
    unsigned int q = hwb[(size_t)s * 64 + lane];
    acc0 = fmaf(w0, bf_lo(q), acc0);
    acc1 = fmaf(w1, bf_hi(q), acc1);
  }
  out[(size_t)i * 128 + lane]      = f2bf(fmaxf(acc0 / den0 + bias[lane], 0.f));
  out[(size_t)i * 128 + 64 + lane] = f2bf(fmaxf(acc1 / den1 + bias[64 + lane], 0.f));
}

// ---------------- per-graph pooling, node-parallel (bf16 input) --------------
#define SEG_CHUNK 128
__global__ __launch_bounds__(128) void seg_sum_fast(const unsigned short* __restrict__ h,
                                                    const int* __restrict__ batch,
                                                    const int* __restrict__ gstart,
                                                    float* __restrict__ reprs) {
  int n0 = blockIdx.x * SEG_CHUNK;
  if (n0 >= NNODES) return;
  int nend = n0 + SEG_CHUNK; if (nend > NNODES) nend = NNODES;
  int tid = threadIdx.x;
  int r = n0;
  while (r < nend) {
    int g = batch[r];
    int segend = gstart[g + 1]; if (segend > nend) segend = nend;
    float a0 = 0.f, a1 = 0.f, a2 = 0.f, a3 = 0.f;
    for (; r + 3 < segend; r += 4) {
      a0 += bf2f(h[(size_t)r * 128 + tid]);
      a1 += bf2f(h[(size_t)(r + 1) * 128 + tid]);
      a2 += bf2f(h[(size_t)(r + 2) * 128 + tid]);
      a3 += bf2f(h[(size_t)(r + 3) * 128 + tid]);
    }
    for (; r < segend; ++r) a0 += bf2f(h[(size_t)r * 128 + tid]);
    atomicAdd(&reprs[g * 128 + tid], (a0 + a1) + (a2 + a3));
  }
}

// ---------------- head MLP + log_softmax -------------------------------------
__global__ __launch_bounds__(128) void head_kernel(const float* __restrict__ reprs,
                                                   const float* __restrict__ pw1,
                                                   const float* __restrict__ pb1,
                                                   const float* __restrict__ pw2,
                                                   const float* __restrict__ pb2,
                                                   float* __restrict__ out) {
  __shared__ float r[128], t1[128], z[NCLS];
  int g = blockIdx.x, tid = threadIdx.x;
  r[tid] = reprs[g * 128 + tid];
  __syncthreads();
  float acc = pb1[tid];
  for (int k = 0; k < 128; ++k) acc = fmaf(r[k], pw1[k * 128 + tid], acc);
  t1[tid] = fmaxf(acc, 0.f);
  __syncthreads();
  if (tid < NCLS) {
    float zz = pb2[tid];
    for (int k = 0; k < 128; ++k) zz = fmaf(t1[k], pw2[k * NCLS + tid], zz);
    z[tid] = zz;
  }
  __syncthreads();
  if (tid == 0) {
    float mx = -1e30f;
    for (int c = 0; c < NCLS; ++c) mx = fmaxf(mx, z[c]);
    float s = 0.f;
    for (int c = 0; c < NCLS; ++c) s += expf(z[c] - mx);
    float ls = logf(s) + mx;
    for (int c = 0; c < NCLS; ++c) out[g * NCLS + c] = z[c] - ls;
  }
}

extern "C" void kernel_launch(void* const* d_in, const int* in_sizes, int n_in,
                              void* d_out, int out_size, void* d_ws, size_t ws_size,
                              hipStream_t stream) {
  const float* x     = (const float*)d_in[0];
  const int*   eidx  = (const int*)d_in[1];
  const int*   batch = (const int*)d_in[2];
  const float* pre_w = (const float*)d_in[3];
  const float* pre_b = (const float*)d_in[4];
  const float* w1    = (const float*)d_in[5];
  const float* asrc1 = (const float*)d_in[6];
  const float* adst1 = (const float*)d_in[7];
  const float* b1    = (const float*)d_in[8];
  const float* w2    = (const float*)d_in[9];
  const float* asrc2 = (const float*)d_in[10];
  const float* adst2 = (const float*)d_in[11];
  const float* b2    = (const float*)d_in[12];
  const float* pw1   = (const float*)d_in[13];
  const float* pb1   = (const float*)d_in[14];
  const float* pw2   = (const float*)d_in[15];
  const float* pb2   = (const float*)d_in[16];
  float* out = (float*)d_out;

  const int* esrc = eidx;
  const int* edst = eidx + NEDGES;

  char* wsp = (char*)d_ws;
  size_t off = 0;
  auto alloc = [&](size_t bytes) -> void* {
    void* p = wsp + off;
    off += (bytes + 255) & ~(size_t)255;
    return p;
  };
  unsigned short* hb = (unsigned short*)alloc((size_t)NNODES * 128 * 2);
  unsigned int* hwb  = (unsigned int*)alloc((size_t)NNODES * 64 * 4);
  float* a_s         = (float*)alloc((size_t)NNODES * 2 * 4);
  float* a_d         = (float*)alloc((size_t)NNODES * 2 * 4);
  float* reprs       = (float*)alloc((size_t)NGRAPH * 128 * 4);
  int* gstart        = (int*)alloc((NGRAPH + 1) * 4);
  int* row_ptr       = (int*)alloc(((size_t)NNODES + 1) * 4);
  int* colv          = (int*)alloc((size_t)NEDGES * 4);
  unsigned short* wt_pre = (unsigned short*)alloc((size_t)128 * FIN * 2);
  unsigned short* wt1    = (unsigned short*)alloc((size_t)128 * HDIM * 2);
  unsigned short* wt2    = (unsigned short*)alloc((size_t)128 * HDIM * 2);
  int* blockHist     = (int*)alloc((size_t)EBLK * NBUCK * 4);
  int* blockBaseCol  = (int*)alloc((size_t)NBUCK * EBLK * 4);
  int* bucket_total  = (int*)alloc(NBUCK * 4);
  int* bucket_ptr    = (int*)alloc((NBUCK + 1) * 4);
  unsigned* stagingG = (unsigned*)alloc((size_t)NEDGES * 4);

  int wb = NNODES / 4;             // wave-per-node kernels: 256 thr = 4 waves
  int sb = (NNODES + SEG_CHUNK - 1) / SEG_CHUNK;
  int gb = (NNODES + 127) / 128;   // 782 GEMM blocks

  // one-shot weight conversion (bf16, transposed)
  convert_transpose<<<(FIN * 128 + 255) / 256, 256, 0, stream>>>(pre_w, wt_pre, FIN);
  convert_transpose<<<(HDIM * 128 + 255) / 256, 256, 0, stream>>>(w1, wt1, HDIM);
  convert_transpose<<<(HDIM * 128 + 255) / 256, 256, 0, stream>>>(w2, wt2, HDIM);

  // graph boundaries + zeroed pooling accumulator
  hipMemsetAsync(reprs, 0, (size_t)NGRAPH * 128 * 4, stream);
  find_starts<<<1, 256, 0, stream>>>(batch, gstart);

  // bucketed CSR build (packed 4B staging; fused deg-scan + scatter)
  bin_count<<<EBLK, 256, 0, stream>>>(edst, blockHist);
  colscan<<<NBUCK, 512, 0, stream>>>(blockHist, blockBaseCol, bucket_total);
  bscan<<<1, 128, 0, stream>>>(bucket_total, bucket_ptr);
  bin_place<<<EBLK, 512, 0, stream>>>(esrc, edst, blockBaseCol, bucket_ptr, stagingG);
  bucket_csr_fused<<<NBUCK, 1024, 0, stream>>>(stagingG, bucket_ptr, row_ptr, colv);

  // pre layer: h0 = relu(x @ pre_w + pre_b)  (bf16 h)
  gemm_mfma<<<gb, 256, 0, stream>>>(x, 0, wt_pre, pre_b, hb, nullptr,
                                    nullptr, nullptr, nullptr, nullptr, NNODES, FIN, 1);
  seg_sum_fast<<<sb, 128, 0, stream>>>(hb, batch, gstart, reprs);

  // GAT layer 1 (bf16 A; alpha fused into GEMM epilogue)
  gemm_mfma<<<gb, 256, 0, stream>>>(hb, 1, wt1, nullptr, nullptr, hwb,
                                    asrc1, adst1, a_s, a_d, NNODES, HDIM, 0);
  aggregate<<<wb, 256, 0, stream>>>(hwb, a_s, a_d, row_ptr, colv, b1, hb);
  seg_sum_fast<<<sb, 128, 0, stream>>>(hb, batch, gstart, reprs);

  // GAT layer 2
  gemm_mfma<<<gb, 256, 0, stream>>>(hb, 1, wt2, nullptr, nullptr, hwb,
                                    asrc2, adst2, a_s, a_d, NNODES, HDIM, 0);
  aggregate<<<wb, 256, 0, stream>>>(hwb, a_s, a_d, row_ptr, colv, b2, hb);
  seg_sum_fast<<<sb, 128, 0, stream>>>(hb, batch, gstart, reprs);

  // head
  head_kernel<<<NGRAPH, 128, 0, stream>>>(reprs, pw1, pb1, pw2, pb2, out);
}

// Round 11
// 505.714 us; speedup vs baseline: 1.4040x; 1.0147x over previous
//
#include <hip/hip_runtime.h>
#include <hip/hip_bf16.h>
#include <math.h>

#define NNODES 100000
#define NEDGES 1600000
#define FIN 256
#define HDIM 128
#define NGRAPH 128
#define NCLS 10
#define NEG 0.2f

#define NBUCK 98            // buckets of 1024 dst nodes
#define EPB 4096            // edges per bin_place block
#define EBLK ((NEDGES + EPB - 1) / EPB)   // 391

typedef short bf8 __attribute__((ext_vector_type(8)));
typedef float f4 __attribute__((ext_vector_type(4)));

__device__ __forceinline__ float lrelu(float x) { return x > 0.f ? x : NEG * x; }

__device__ __forceinline__ unsigned short f2bf(float f) {
  union { float f; unsigned int u; } v; v.f = f;
  unsigned int r = v.u + 0x7fffu + ((v.u >> 16) & 1u);   // round-nearest-even
  return (unsigned short)(r >> 16);
}
__device__ __forceinline__ float bf2f(unsigned short u) {
  union { unsigned int u; float f; } v; v.u = ((unsigned int)u) << 16; return v.f;
}
__device__ __forceinline__ float bf_lo(unsigned int p) {
  union { unsigned int u; float f; } v; v.u = p << 16; return v.f;
}
__device__ __forceinline__ float bf_hi(unsigned int p) {
  union { unsigned int u; float f; } v; v.u = p & 0xffff0000u; return v.f;
}

// ---------------- one-shot weight convert+transpose: w[K][128] -> wt[128][K] -
__global__ __launch_bounds__(256) void convert_transpose(const float* __restrict__ w,
                                                         unsigned short* __restrict__ wt,
                                                         int K) {
  int i = blockIdx.x * 256 + threadIdx.x;
  if (i >= K * 128) return;
  int k = i >> 7, n = i & 127;
  wt[n * K + k] = f2bf(w[(size_t)k * 128 + n]);
}

// ---------------- MFMA GEMM, register-prefetch pipelined K-loop --------------
// A: fp32 (a_bf16=0) or bf16 row-major (a_bf16=1).
// Output: Cb (bf16 h, +bias+relu) OR Cp (packed ushort2{h0,h1}) + fused logits.
// Tile k+1 is loaded into registers right after the consume barrier; its vmcnt
// wait lands at the LDS store of the NEXT iteration, overlapped with MFMAs.
__global__ __launch_bounds__(256) void gemm_mfma(const void* __restrict__ Av,
                                                 int a_bf16,
                                                 const unsigned short* __restrict__ Bt,
                                                 const float* __restrict__ bias,
                                                 unsigned short* __restrict__ Cb,
                                                 unsigned int* __restrict__ Cp,
                                                 const float* __restrict__ a_src,
                                                 const float* __restrict__ a_dst,
                                                 float* __restrict__ o_as,
                                                 float* __restrict__ o_ad,
                                                 int M, int K, int dorelu) {
  __shared__ bf8 As[512];
  __shared__ bf8 Bs[512];
  int tid = threadIdx.x;
  int wv = tid >> 6, lane = tid & 63;
  int quad = lane >> 4, m16 = lane & 15;
  int row0 = blockIdx.x * 128;

  // staging coordinates: blob b=tid covers tile t0=tid>>6, blob b=tid+256 tile t0+4
  int l0 = tid & 63, t0 = tid >> 6, t1 = t0 + 4;
  int rA0 = row0 + t0 * 16 + (l0 & 15); if (rA0 > M - 1) rA0 = M - 1;
  int rA1 = row0 + t1 * 16 + (l0 & 15); if (rA1 > M - 1) rA1 = M - 1;
  int nB0 = t0 * 16 + (l0 & 15);
  int nB1 = t1 * 16 + (l0 & 15);
  int cOff = (l0 >> 4) * 8;

  float4 fA0a, fA0b, fA1a, fA1b;
  bf8 hA0, hA1, pB0, pB1;

  auto loadA = [&](int kb) {
    if (a_bf16) {
      const unsigned short* base = (const unsigned short*)Av;
      hA0 = *reinterpret_cast<const bf8*>(base + (size_t)rA0 * K + kb + cOff);
      hA1 = *reinterpret_cast<const bf8*>(base + (size_t)rA1 * K + kb + cOff);
    } else {
      const float* base = (const float*)Av;
      const float* p0 = base + (size_t)rA0 * K + kb + cOff;
      const float* p1 = base + (size_t)rA1 * K + kb + cOff;
      fA0a = *reinterpret_cast<const float4*>(p0);
      fA0b = *reinterpret_cast<const float4*>(p0 + 4);
      fA1a = *reinterpret_cast<const float4*>(p1);
      fA1b = *reinterpret_cast<const float4*>(p1 + 4);
    }
  };
  auto loadB = [&](int kb) {
    pB0 = *reinterpret_cast<const bf8*>(&Bt[(size_t)nB0 * K + kb + cOff]);
    pB1 = *reinterpret_cast<const bf8*>(&Bt[(size_t)nB1 * K + kb + cOff]);
  };
  auto cvt8 = [&](float4 a, float4 b) -> bf8 {
    bf8 v;
    v[0] = (short)f2bf(a.x); v[1] = (short)f2bf(a.y);
    v[2] = (short)f2bf(a.z); v[3] = (short)f2bf(a.w);
    v[4] = (short)f2bf(b.x); v[5] = (short)f2bf(b.y);
    v[6] = (short)f2bf(b.z); v[7] = (short)f2bf(b.w);
    return v;
  };

  f4 acc[2][8];
#pragma unroll
  for (int a = 0; a < 2; ++a)
#pragma unroll
    for (int b = 0; b < 8; ++b) acc[a][b] = (f4){0.f, 0.f, 0.f, 0.f};

  loadA(0); loadB(0);
  for (int kb = 0; kb < K; kb += 32) {
    __syncthreads();          // all waves done reading LDS from previous iter
    if (a_bf16) { As[tid] = hA0; As[tid + 256] = hA1; }
    else        { As[tid] = cvt8(fA0a, fA0b); As[tid + 256] = cvt8(fA1a, fA1b); }
    Bs[tid] = pB0; Bs[tid + 256] = pB1;
    __syncthreads();
    int kn = kb + 32;
    if (kn < K) { loadA(kn); loadB(kn); }   // prefetch: waits in NEXT iter's store
    bf8 af0 = As[(wv * 2 + 0) * 64 + lane];
    bf8 af1 = As[(wv * 2 + 1) * 64 + lane];
#pragma unroll
    for (int tn = 0; tn < 8; ++tn) {
      bf8 bfm = Bs[tn * 64 + lane];
      acc[0][tn] = __builtin_amdgcn_mfma_f32_16x16x32_bf16(af0, bfm, acc[0][tn], 0, 0, 0);
      acc[1][tn] = __builtin_amdgcn_mfma_f32_16x16x32_bf16(af1, bfm, acc[1][tn], 0, 0, 0);
    }
  }

  if (Cp) {
    if (a_src) {
      float aS[8], aD[8];
#pragma unroll
      for (int tn = 0; tn < 4; ++tn) {
        aS[tn]     = a_src[tn * 16 + m16];
        aS[tn + 4] = a_src[64 + tn * 16 + m16];
        aD[tn]     = a_dst[tn * 16 + m16];
        aD[tn + 4] = a_dst[64 + tn * 16 + m16];
      }
#pragma unroll
      for (int mt = 0; mt < 2; ++mt)
#pragma unroll
        for (int r = 0; r < 4; ++r) {
          int row = row0 + wv * 32 + mt * 16 + quad * 4 + r;
          float ps0 = 0.f, ps1 = 0.f, pd0 = 0.f, pd1 = 0.f;
#pragma unroll
          for (int tn = 0; tn < 4; ++tn) {
            float v0 = acc[mt][tn][r], v1 = acc[mt][tn + 4][r];
            ps0 = fmaf(v0, aS[tn], ps0);
            ps1 = fmaf(v1, aS[tn + 4], ps1);
            pd0 = fmaf(v0, aD[tn], pd0);
            pd1 = fmaf(v1, aD[tn + 4], pd1);
          }
#pragma unroll
          for (int o = 8; o; o >>= 1) {
            ps0 += __shfl_xor(ps0, o); ps1 += __shfl_xor(ps1, o);
            pd0 += __shfl_xor(pd0, o); pd1 += __shfl_xor(pd1, o);
          }
          if (m16 == 0 && row < M) {
            o_as[2 * row] = ps0; o_as[2 * row + 1] = ps1;
            o_ad[2 * row] = pd0; o_ad[2 * row + 1] = pd1;
          }
        }
    }
#pragma unroll
    for (int mt = 0; mt < 2; ++mt)
#pragma unroll
      for (int tn = 0; tn < 4; ++tn)
#pragma unroll
        for (int r = 0; r < 4; ++r) {
          int row = row0 + wv * 32 + mt * 16 + quad * 4 + r;
          if (row < M) {
            unsigned int p = (unsigned int)f2bf(acc[mt][tn][r]) |
                             ((unsigned int)f2bf(acc[mt][tn + 4][r]) << 16);
            Cp[(size_t)row * 64 + tn * 16 + m16] = p;
          }
        }
  } else {
#pragma unroll
    for (int mt = 0; mt < 2; ++mt)
#pragma unroll
      for (int tn = 0; tn < 8; ++tn) {
        float bv = bias ? bias[tn * 16 + m16] : 0.f;
#pragma unroll
        for (int r = 0; r < 4; ++r) {
          int row = row0 + wv * 32 + mt * 16 + quad * 4 + r;
          if (row < M) {
            float v = acc[mt][tn][r] + bv;
            if (dorelu) v = fmaxf(v, 0.f);
            Cb[(size_t)row * 128 + tn * 16 + m16] = f2bf(v);
          }
        }
      }
  }
}

// ---------------- graph boundaries (batch is sorted) -------------------------
__global__ void find_starts(const int* __restrict__ batch, int* __restrict__ gstart) {
  int g = threadIdx.x;
  if (g > NGRAPH) return;
  if (g == NGRAPH) { gstart[g] = NNODES; return; }
  int lo = 0, hi = NNODES;
  while (lo < hi) { int mid = (lo + hi) >> 1; if (batch[mid] < g) lo = mid + 1; else hi = mid; }
  gstart[g] = lo;
}

// ======== CSR build, bucketed two-phase (no random global atomics) ==========
__global__ __launch_bounds__(256) void bin_count(const int* __restrict__ edst,
                                                 int* __restrict__ blockHist) {
  __shared__ int hist[NBUCK];
  int t = threadIdx.x, blk = blockIdx.x;
  if (t < NBUCK) hist[t] = 0;
  __syncthreads();
  int e0 = blk * EPB;
#pragma unroll
  for (int it = 0; it < EPB / 256; ++it) {
    int e = e0 + it * 256 + t;
    if (e < NEDGES) atomicAdd(&hist[((unsigned)edst[e]) >> 10], 1);
  }
  __syncthreads();
  if (t < NBUCK) blockHist[blk * NBUCK + t] = hist[t];
}

__global__ __launch_bounds__(512) void colscan(const int* __restrict__ blockHist,
                                               int* __restrict__ blockBaseCol,
                                               int* __restrict__ bucket_total) {
  __shared__ int s[512];
  int b = blockIdx.x, t = threadIdx.x;
  int v = (t < EBLK) ? blockHist[t * NBUCK + b] : 0;
  s[t] = v;
  __syncthreads();
  for (int off = 1; off < 512; off <<= 1) {
    int u = (t >= off) ? s[t - off] : 0;
    __syncthreads();
    s[t] += u;
    __syncthreads();
  }
  if (t < EBLK) blockBaseCol[b * EBLK + t] = s[t] - v;
  if (t == 511) bucket_total[b] = s[511];
}

__global__ __launch_bounds__(128) void bscan(const int* __restrict__ bucket_total,
                                             int* __restrict__ bucket_ptr) {
  __shared__ int s[128];
  int t = threadIdx.x;
  int v = (t < NBUCK) ? bucket_total[t] : 0;
  s[t] = v;
  __syncthreads();
  for (int off = 1; off < 128; off <<= 1) {
    int u = (t >= off) ? s[t - off] : 0;
    __syncthreads();
    s[t] += u;
    __syncthreads();
  }
  if (t < NBUCK) bucket_ptr[t] = s[t] - v;
  if (t == 127) bucket_ptr[NBUCK] = s[127];
}

// staging entry: (dst_local_10bits << 17) | src_17bits  (NNODES < 2^17)
__global__ __launch_bounds__(512) void bin_place(const int* __restrict__ esrc,
                                                 const int* __restrict__ edst,
                                                 const int* __restrict__ blockBaseCol,
                                                 const int* __restrict__ bucket_ptr,
                                                 unsigned* __restrict__ stagingG) {
  __shared__ int hist[NBUCK + 1], lbase[NBUCK + 1], lcur[NBUCK + 1], cbase[NBUCK];
  __shared__ int tmp[128];
  __shared__ uint2 st[EPB];
  int t = threadIdx.x, blk = blockIdx.x;
  if (t < NBUCK + 1) hist[t] = 0;
  __syncthreads();
  int e0 = blk * EPB;
#pragma unroll
  for (int it = 0; it < EPB / 512; ++it) {
    int e = e0 + it * 512 + t;
    int b = NBUCK;
    if (e < NEDGES) b = ((unsigned)edst[e]) >> 10;
    atomicAdd(&hist[b], 1);
  }
  __syncthreads();
  if (t < 128) tmp[t] = (t < NBUCK + 1) ? hist[t] : 0;
  __syncthreads();
  for (int off = 1; off < 128; off <<= 1) {
    int u = 0;
    if (t < 128 && t >= off) u = tmp[t - off];
    __syncthreads();
    if (t < 128) tmp[t] += u;
    __syncthreads();
  }
  if (t < NBUCK + 1) { int ex = tmp[t] - hist[t]; lbase[t] = ex; lcur[t] = ex; }
  if (t < NBUCK) cbase[t] = bucket_ptr[t] + blockBaseCol[t * EBLK + blk];
  __syncthreads();
#pragma unroll
  for (int it = 0; it < EPB / 512; ++it) {
    int e = e0 + it * 512 + t;
    unsigned s = 0, d = 0xFFFFFFFFu;
    if (e < NEDGES) { s = (unsigned)esrc[e]; d = (unsigned)edst[e]; }
    int b = (d == 0xFFFFFFFFu) ? NBUCK : (int)(d >> 10);
    int slot = atomicAdd(&lcur[b], 1);
    st[slot] = make_uint2(s, d);
  }
  __syncthreads();
  for (int i = t; i < EPB; i += 512) {
    uint2 ed = st[i];
    if (ed.y == 0xFFFFFFFFu) continue;
    int b = (int)(ed.y >> 10);
    stagingG[cbase[b] + (i - lbase[b])] = ((ed.y & 1023u) << 17) | ed.x;
  }
}

// fused: per-bucket degree histogram + LDS scan -> row_ptr, then scatter
__global__ __launch_bounds__(1024) void bucket_csr_fused(const unsigned* __restrict__ stagingG,
                                                         const int* __restrict__ bucket_ptr,
                                                         int* __restrict__ row_ptr,
                                                         int* __restrict__ colv) {
  __shared__ int dl[1024];
  __shared__ int cur[1024];
  int b = blockIdx.x, t = threadIdx.x;
  dl[t] = 0;
  __syncthreads();
  int s0 = bucket_ptr[b], s1 = bucket_ptr[b + 1];
  for (int j = s0 + t; j < s1; j += 1024)
    atomicAdd(&dl[stagingG[j] >> 17], 1);
  __syncthreads();
  int myDeg = dl[t];
  for (int off = 1; off < 1024; off <<= 1) {
    int u = (t >= off) ? dl[t - off] : 0;
    __syncthreads();
    dl[t] += u;
    __syncthreads();
  }
  int rp = s0 + dl[t] - myDeg;
  cur[t] = rp;
  int n = (b << 10) + t;
  if (n < NNODES) row_ptr[n] = rp;
  if (n == NNODES - 1) row_ptr[NNODES] = rp + myDeg;
  __syncthreads();
  for (int j = s0 + t; j < s1; j += 1024) {
    unsigned v = stagingG[j];
    int pos = atomicAdd(&cur[v >> 17], 1);
    colv[pos] = (int)(v & 0x1FFFFu);
  }
}

// ---------------- tiered gather: compile-time lane idx -> readlane/SGPR ------
template<int T>
__device__ __forceinline__ void gather_T(const unsigned int* __restrict__ hwb,
                                         int lane, int sl, float w0l, float w1l,
                                         float& acc0, float& acc1) {
#pragma unroll
  for (int t = 0; t < T; ++t) {
    int s = __builtin_amdgcn_readlane(sl, t);                                   // SGPR
    float w0 = __uint_as_float(__builtin_amdgcn_readlane(__float_as_uint(w0l), t));
    float w1 = __uint_as_float(__builtin_amdgcn_readlane(__float_as_uint(w1l), t));
    unsigned q = hwb[(size_t)s * 64 + lane];   // saddr + lane offset
    acc0 = fmaf(w0, bf_lo(q), acc0);
    acc1 = fmaf(w1, bf_hi(q), acc1);
  }
}

// ---------------- softmax aggregation: one wave per dst node -----------------
__global__ __launch_bounds__(256) void aggregate(const unsigned int* __restrict__ hwb,
                                                 const float* __restrict__ a_s,
                                                 const float* __restrict__ a_d,
                                                 const int* __restrict__ row_ptr,
                                                 const int* __restrict__ colv,
                                                 const float* __restrict__ bias,
                                                 unsigned short* __restrict__ out) {
  int i = (blockIdx.x * 256 + threadIdx.x) >> 6;
  int lane = threadIdx.x & 63;
  if (i >= NNODES) return;
  float ad0 = a_d[2 * i], ad1 = a_d[2 * i + 1];
  float es0 = lrelu(a_s[2 * i] + ad0), es1 = lrelu(a_s[2 * i + 1] + ad1);  // self edge
  int start = row_ptr[i], end = row_ptr[i + 1];
  int deg = end - start;

  int sl = 0; float e0l = -1e30f, e1l = -1e30f;
  if (lane < deg) {
    sl = colv[start + lane];
    float2 av = *reinterpret_cast<const float2*>(&a_s[2 * sl]);
    e0l = lrelu(av.x + ad0); e1l = lrelu(av.y + ad1);
  }
  float m0 = fmaxf(es0, e0l), m1 = fmaxf(es1, e1l);
  for (int j = start + 64 + lane; j < end; j += 64) {
    int s = colv[j];
    float2 av = *reinterpret_cast<const float2*>(&a_s[2 * s]);
    m0 = fmaxf(m0, lrelu(av.x + ad0));
    m1 = fmaxf(m1, lrelu(av.y + ad1));
  }
  for (int o = 32; o; o >>= 1) {
    m0 = fmaxf(m0, __shfl_xor(m0, o));
    m1 = fmaxf(m1, __shfl_xor(m1, o));
  }
  float w0l = lane < deg ? __expf(e0l - m0) : 0.f;
  float w1l = lane < deg ? __expf(e1l - m1) : 0.f;
  float d0 = w0l, d1 = w1l;
  for (int o = 32; o; o >>= 1) { d0 += __shfl_xor(d0, o); d1 += __shfl_xor(d1, o); }
  float ws0 = __expf(es0 - m0), ws1 = __expf(es1 - m1);
  float den0 = d0 + ws0, den1 = d1 + ws1;

  unsigned int ps = hwb[(size_t)i * 64 + lane];
  float acc0 = ws0 * bf_lo(ps), acc1 = ws1 * bf_hi(ps);
  int dmin = deg < 64 ? deg : 64;
  switch ((dmin + 7) >> 3) {
    case 1: gather_T<8 >(hwb, lane, sl, w0l, w1l, acc0, acc1); break;
    case 2: gather_T<16>(hwb, lane, sl, w0l, w1l, acc0, acc1); break;
    case 3: gather_T<24>(hwb, lane, sl, w0l, w1l, acc0, acc1); break;
    case 4: gather_T<32>(hwb, lane, sl, w0l, w1l, acc0, acc1); break;
    case 5: gather_T<40>(hwb, lane, sl, w0l, w1l, acc0, acc1); break;
    case 6: gather_T<48>(hwb, lane, sl, w0l, w1l, acc0, acc1); break;
    case 7: gather_T<56>(hwb, lane, sl, w0l, w1l, acc0, acc1); break;
    case 8: gather_T<64>(hwb, lane, sl, w0l, w1l, acc0, acc1); break;
    default: break;
  }
  for (int j = start + 64; j < end; ++j) {   // rare overflow path (deg > 64)
    int s = colv[j];
    float2 av = *reinterpret_cast<const float2*>(&a_s[2 * s]);
    float w0 = __expf(lrelu(av.x + ad0) - m0);
    float w1 = __expf(lrelu(av.y + ad1) - m1);
    den0 += w0; den1 += w1;
    unsigned int q = hwb[(size_t)s * 64 + lane];
    acc0 = fmaf(w0, bf_lo(q), acc0);
    acc1 = fmaf(w1, bf_hi(q), acc1);
  }
  out[(size_t)i * 128 + lane]      = f2bf(fmaxf(acc0 / den0 + bias[lane], 0.f));
  out[(size_t)i * 128 + 64 + lane] = f2bf(fmaxf(acc1 / den1 + bias[64 + lane], 0.f));
}

// ---------------- per-graph pooling, node-parallel (bf16 input) --------------
#define SEG_CHUNK 128
__global__ __launch_bounds__(128) void seg_sum_fast(const unsigned short* __restrict__ h,
                                                    const int* __restrict__ batch,
                                                    const int* __restrict__ gstart,
                                                    float* __restrict__ reprs) {
  int n0 = blockIdx.x * SEG_CHUNK;
  if (n0 >= NNODES) return;
  int nend = n0 + SEG_CHUNK; if (nend > NNODES) nend = NNODES;
  int tid = threadIdx.x;
  int r = n0;
  while (r < nend) {
    int g = batch[r];
    int segend = gstart[g + 1]; if (segend > nend) segend = nend;
    float a0 = 0.f, a1 = 0.f, a2 = 0.f, a3 = 0.f;
    for (; r + 3 < segend; r += 4) {
      a0 += bf2f(h[(size_t)r * 128 + tid]);
      a1 += bf2f(h[(size_t)(r + 1) * 128 + tid]);
      a2 += bf2f(h[(size_t)(r + 2) * 128 + tid]);
      a3 += bf2f(h[(size_t)(r + 3) * 128 + tid]);
    }
    for (; r < segend; ++r) a0 += bf2f(h[(size_t)r * 128 + tid]);
    atomicAdd(&reprs[g * 128 + tid], (a0 + a1) + (a2 + a3));
  }
}

// ---------------- head MLP + log_softmax -------------------------------------
__global__ __launch_bounds__(128) void head_kernel(const float* __restrict__ reprs,
                                                   const float* __restrict__ pw1,
                                                   const float* __restrict__ pb1,
                                                   const float* __restrict__ pw2,
                                                   const float* __restrict__ pb2,
                                                   float* __restrict__ out) {
  __shared__ float r[128], t1[128], z[NCLS];
  int g = blockIdx.x, tid = threadIdx.x;
  r[tid] = reprs[g * 128 + tid];
  __syncthreads();
  float acc = pb1[tid];
  for (int k = 0; k < 128; ++k) acc = fmaf(r[k], pw1[k * 128 + tid], acc);
  t1[tid] = fmaxf(acc, 0.f);
  __syncthreads();
  if (tid < NCLS) {
    float zz = pb2[tid];
    for (int k = 0; k < 128; ++k) zz = fmaf(t1[k], pw2[k * NCLS + tid], zz);
    z[tid] = zz;
  }
  __syncthreads();
  if (tid == 0) {
    float mx = -1e30f;
    for (int c = 0; c < NCLS; ++c) mx = fmaxf(mx, z[c]);
    float s = 0.f;
    for (int c = 0; c < NCLS; ++c) s += expf(z[c] - mx);
    float ls = logf(s) + mx;
    for (int c = 0; c < NCLS; ++c) out[g * NCLS + c] = z[c] - ls;
  }
}

extern "C" void kernel_launch(void* const* d_in, const int* in_sizes, int n_in,
                              void* d_out, int out_size, void* d_ws, size_t ws_size,
                              hipStream_t stream) {
  const float* x     = (const float*)d_in[0];
  const int*   eidx  = (const int*)d_in[1];
  const int*   batch = (const int*)d_in[2];
  const float* pre_w = (const float*)d_in[3];
  const float* pre_b = (const float*)d_in[4];
  const float* w1    = (const float*)d_in[5];
  const float* asrc1 = (const float*)d_in[6];
  const float* adst1 = (const float*)d_in[7];
  const float* b1    = (const float*)d_in[8];
  const float* w2    = (const float*)d_in[9];
  const float* asrc2 = (const float*)d_in[10];
  const float* adst2 = (const float*)d_in[11];
  const float* b2    = (const float*)d_in[12];
  const float* pw1   = (const float*)d_in[13];
  const float* pb1   = (const float*)d_in[14];
  const float* pw2   = (const float*)d_in[15];
  const float* pb2   = (const float*)d_in[16];
  float* out = (float*)d_out;

  const int* esrc = eidx;
  const int* edst = eidx + NEDGES;

  char* wsp = (char*)d_ws;
  size_t off = 0;
  auto alloc = [&](size_t bytes) -> void* {
    void* p = wsp + off;
    off += (bytes + 255) & ~(size_t)255;
    return p;
  };
  unsigned short* hb = (unsigned short*)alloc((size_t)NNODES * 128 * 2);
  unsigned int* hwb  = (unsigned int*)alloc((size_t)NNODES * 64 * 4);
  float* a_s         = (float*)alloc((size_t)NNODES * 2 * 4);
  float* a_d         = (float*)alloc((size_t)NNODES * 2 * 4);
  float* reprs       = (float*)alloc((size_t)NGRAPH * 128 * 4);
  int* gstart        = (int*)alloc((NGRAPH + 1) * 4);
  int* row_ptr       = (int*)alloc(((size_t)NNODES + 1) * 4);
  int* colv          = (int*)alloc((size_t)NEDGES * 4);
  unsigned short* wt_pre = (unsigned short*)alloc((size_t)128 * FIN * 2);
  unsigned short* wt1    = (unsigned short*)alloc((size_t)128 * HDIM * 2);
  unsigned short* wt2    = (unsigned short*)alloc((size_t)128 * HDIM * 2);
  int* blockHist     = (int*)alloc((size_t)EBLK * NBUCK * 4);
  int* blockBaseCol  = (int*)alloc((size_t)NBUCK * EBLK * 4);
  int* bucket_total  = (int*)alloc(NBUCK * 4);
  int* bucket_ptr    = (int*)alloc((NBUCK + 1) * 4);
  unsigned* stagingG = (unsigned*)alloc((size_t)NEDGES * 4);

  int wb = NNODES / 4;             // wave-per-node kernels: 256 thr = 4 waves
  int sb = (NNODES + SEG_CHUNK - 1) / SEG_CHUNK;
  int gb = (NNODES + 127) / 128;   // 782 GEMM blocks

  // one-shot weight conversion (bf16, transposed)
  convert_transpose<<<(FIN * 128 + 255) / 256, 256, 0, stream>>>(pre_w, wt_pre, FIN);
  convert_transpose<<<(HDIM * 128 + 255) / 256, 256, 0, stream>>>(w1, wt1, HDIM);
  convert_transpose<<<(HDIM * 128 + 255) / 256, 256, 0, stream>>>(w2, wt2, HDIM);

  // graph boundaries + zeroed pooling accumulator
  hipMemsetAsync(reprs, 0, (size_t)NGRAPH * 128 * 4, stream);
  find_starts<<<1, 256, 0, stream>>>(batch, gstart);

  // bucketed CSR build (packed 4B staging; fused deg-scan + scatter)
  bin_count<<<EBLK, 256, 0, stream>>>(edst, blockHist);
  colscan<<<NBUCK, 512, 0, stream>>>(blockHist, blockBaseCol, bucket_total);
  bscan<<<1, 128, 0, stream>>>(bucket_total, bucket_ptr);
  bin_place<<<EBLK, 512, 0, stream>>>(esrc, edst, blockBaseCol, bucket_ptr, stagingG);
  bucket_csr_fused<<<NBUCK, 1024, 0, stream>>>(stagingG, bucket_ptr, row_ptr, colv);

  // pre layer: h0 = relu(x @ pre_w + pre_b)  (bf16 h)
  gemm_mfma<<<gb, 256, 0, stream>>>(x, 0, wt_pre, pre_b, hb, nullptr,
                                    nullptr, nullptr, nullptr, nullptr, NNODES, FIN, 1);
  seg_sum_fast<<<sb, 128, 0, stream>>>(hb, batch, gstart, reprs);

  // GAT layer 1 (bf16 A; alpha fused into GEMM epilogue)
  gemm_mfma<<<gb, 256, 0, stream>>>(hb, 1, wt1, nullptr, nullptr, hwb,
                                    asrc1, adst1, a_s, a_d, NNODES, HDIM, 0);
  aggregate<<<wb, 256, 0, stream>>>(hwb, a_s, a_d, row_ptr, colv, b1, hb);
  seg_sum_fast<<<sb, 128, 0, stream>>>(hb, batch, gstart, reprs);

  // GAT layer 2
  gemm_mfma<<<gb, 256, 0, stream>>>(hb, 1, wt2, nullptr, nullptr, hwb,
                                    asrc2, adst2, a_s, a_d, NNODES, HDIM, 0);
  aggregate<<<wb, 256, 0, stream>>>(hwb, a_s, a_d, row_ptr, colv, b2, hb);
  seg_sum_fast<<<sb, 128, 0, stream>>>(hb, batch, gstart, reprs);

  // head
  head_kernel<<<NGRAPH, 128, 0, stream>>>(reprs, pw1, pb1, pw2, pb2, out);
}